// Round 14
// baseline (424.420 us; speedup 1.0000x reference)
//
#include <hip/hip_runtime.h>
#include <hip/hip_bf16.h>
#include <cmath>

// Problem constants
#define BB 4
#define TT 16
#define HH 32
#define WW 64
#define DD 256
#define NHEAD 8
#define EE 32
#define MP 64      // M_PANEL
#define ML 16      // M_LAST
#define SPAT 32768 // TT*HH*WW
#define S2D 512    // TT*HH

// d_ws layout (float offsets)
constexpr size_t OFF_FTRE = 0;        // [p][t] 64x16
constexpr size_t OFF_FTIM = 1024;
constexpr size_t OFF_FHRE = 2048;     // [p][hs] 64x32
constexpr size_t OFF_FHIM = 4096;
constexpr size_t OFF_CW   = 6144;     // [f][ws] 16x64
constexpr size_t OFF_W64I = 7168;     // [ws][f2] 64x32 interleaved re,im
constexpr size_t OFF_W16  = 9216;     // [t][kt] float2 16x16
constexpr size_t OFF_FHT  = 9728;     // [hs][p] float2 32x64
constexpr size_t OFF_GB   = 16384;                 // gbuf fp32 [b][c][s][f] 8.4M floats
constexpr size_t OFF_FW   = OFF_GB + 8388608;      // Fw fp32 [b][s][d][f2] 16.8M floats; after k3f reused: ob bf16
constexpr size_t OFF_X    = OFF_FW + 16777216;     // [bd][p][f] cplx 2.1M floats
constexpr size_t OFF_V    = OFF_X + 2097152;       // [bd][p][f] cplx 2.1M floats
constexpr size_t OFF_WT   = OFF_V + 2097152;       // WqT bf16 65536 + WoT bf16 65536

typedef short short8 __attribute__((ext_vector_type(8)));
typedef float f32x4 __attribute__((ext_vector_type(4)));

static __device__ __forceinline__ unsigned short f2bf(float x) {
  union { float f; unsigned u; } v; v.f = x;
  unsigned r = v.u + 0x7fffu + ((v.u >> 16) & 1u);
  return (unsigned short)(r >> 16);
}

static __device__ __forceinline__ void gl_lds16(const void* g, void* l) {
  __builtin_amdgcn_global_load_lds((const __attribute__((address_space(1))) void*)g,
                                   (__attribute__((address_space(3))) void*)l, 16, 0, 0);
}

// XCD-pinning bijective swizzle for 4-sibling tiles: flat in [0,4096) ->
// tile in [0,1024), dg in [0,4) with all 4 dg of a tile on the same XCD (flat%8).
static __device__ __forceinline__ void xcd_tile_dg(int flat, int& tile, int& dg) {
  int w8 = flat >> 3, xl = flat & 7;
  tile = ((w8 >> 2) << 3) | xl;
  dg = w8 & 3;
}

// ---------------- K0: twiddle tables ----------------
__global__ __launch_bounds__(256) void k0_tables(const int* __restrict__ panel, float* __restrict__ tab) {
  __shared__ int kt[MP], kh[MP];
  int tid = threadIdx.x;
  if (tid < MP) { int s = panel[tid]; kt[tid] = s >> 5; kh[tid] = s & 31; }
  __syncthreads();
  const double PI2 = 6.283185307179586476925286766559;
  for (int i = tid; i < 1024; i += 256) {  // FT [p][t]
    int p = i >> 4, t = i & 15;
    double a = -PI2 * (double)((t * kt[p]) & 15) / 16.0;
    tab[OFF_FTRE + i] = (float)cos(a);
    tab[OFF_FTIM + i] = (float)sin(a);
  }
  for (int i = tid; i < 2048; i += 256) {  // FH [p][hs]
    int p = i >> 5, hs = i & 31;
    double a = -PI2 * (double)((hs * kh[p]) & 31) / 32.0;
    tab[OFF_FHRE + i] = (float)cos(a);
    tab[OFF_FHIM + i] = (float)sin(a);
  }
  for (int i = tid; i < 1024; i += 256) {  // CW [f][ws]
    int f = i >> 6, wsx = i & 63;
    double a = PI2 * (double)((f * wsx) & 63) / 64.0;
    tab[OFF_CW + i] = (f == 0) ? (1.0f / 64.0f) : (float)(2.0 * cos(a) / 64.0);
  }
  for (int i = tid; i < 2048; i += 256) {  // W64I [ws][f2]
    int wsx = i >> 5, f2 = i & 31; int f = f2 >> 1;
    double a = -PI2 * (double)((wsx * f) & 63) / 64.0;
    tab[OFF_W64I + i] = (f2 & 1) ? (float)sin(a) : (float)cos(a);
  }
  if (tid < 256) {                         // W16 [t][kt] float2
    int t = tid >> 4, k = tid & 15;
    double a = -PI2 * (double)((t * k) & 15) / 16.0;
    tab[OFF_W16 + 2 * tid]     = (float)cos(a);
    tab[OFF_W16 + 2 * tid + 1] = (float)sin(a);
  }
  for (int i = tid; i < 2048; i += 256) {  // FHT [hs][p] float2
    int hs = i >> 6, p = i & 63;
    double a = -PI2 * (double)((hs * kh[p]) & 31) / 32.0;
    tab[OFF_FHT + 2 * i]     = (float)cos(a);
    tab[OFF_FHT + 2 * i + 1] = (float)sin(a);
  }
}

// ---------------- conv_w: Wq/Wo fp32 [k][d] -> WT bf16 [d][k] ----------------
__global__ __launch_bounds__(256) void conv_w(const float* __restrict__ Wq, const float* __restrict__ Wo,
                                              unsigned short* __restrict__ wqt, unsigned short* __restrict__ wot) {
  __shared__ float tile[32][33];
  const float* src = blockIdx.z ? Wo : Wq;
  unsigned short* dst = blockIdx.z ? wot : wqt;
  int k0 = blockIdx.x * 32, d0 = blockIdx.y * 32;
  int tx = threadIdx.x & 31, r4 = threadIdx.x >> 5;
  #pragma unroll
  for (int it = 0; it < 4; it++) {
    int row = r4 + it * 8;
    tile[row][tx] = src[(size_t)(k0 + row) * 256 + d0 + tx];
  }
  __syncthreads();
  #pragma unroll
  for (int it = 0; it < 4; it++) {
    int row = r4 + it * 8;
    dst[(size_t)(d0 + row) * 256 + k0 + tx] = f2bf(tile[tx][row]);
  }
}

// ---------------- K1f3: Q=x@Wq+bq (bf16 MFMA) + reg-tiled ws-DFT (s-split) -> Fw[b][s][d][f2] ----------------
// Flat grid 4096, XCD-pinned siblings. LDS 32.75 KB. (round-12 proven version)
__global__ __launch_bounds__(256) void k1f3(const float* __restrict__ x,
                                            const unsigned short* __restrict__ wqt,
                                            const float* __restrict__ bq,
                                            const float* __restrict__ tabp,
                                            float* __restrict__ Fwg) {
  __shared__ char smem[32768];
  char*  Al = smem;                      // [128 sp][128 B] bf16, XOR-swizzled (16384 B)
  char*  Bl = smem + 16384;              // [64 d][128 B] bf16, XOR-swizzled (8192 B)
  float* QL = (float*)smem;              // [64][68] fp32 overlay of Al+Bl (17408 B <= 24576)
  float* WL = (float*)(smem + 24576);    // [64 ws][32 f2] fp32 (8192 B, persistent)
  int tile, dg;
  xcd_tile_dg(blockIdx.x, tile, dg);
  int d0 = dg << 6;
  int b = tile >> 8, st = tile & 255;
  int sp0 = st << 7;
  int tid = threadIdx.x;
  int lane = tid & 63, w = tid >> 6;
  int l15 = lane & 15, kg = lane >> 4;
  int swz = (l15 & 7) << 4;
  for (int i = tid; i < 2048; i += 256) WL[i] = tabp[OFF_W64I + i];
  f32x4 acc[2][4];
  #pragma unroll
  for (int mi = 0; mi < 2; mi++)
    #pragma unroll
    for (int ni = 0; ni < 4; ni++) acc[mi][ni] = (f32x4){0.f, 0.f, 0.f, 0.f};
  const float* xbase = x + ((size_t)b * 32768 + sp0) * 256;
  const char* Bbase = (const char*)(wqt + (size_t)d0 * 256);
  for (int k0 = 0; k0 < 256; k0 += 64) {
    // B-stage first: async gl_lds in flight during the A convert below
    #pragma unroll
    for (int it = 0; it < 2; it++) {
      int o = it * 4096 + tid * 16;
      int row = o >> 7, cb = o & 127;
      gl_lds16(Bbase + (size_t)row * 512 + k0 * 2 + (cb ^ ((row & 7) << 4)), Bl + o);
    }
    // A-stage: x fp32 -> bf16 -> swizzled LDS (in-register convert)
    #pragma unroll
    for (int it = 0; it < 4; it++) {
      int idx = it * 256 + tid;
      int row = idx >> 3, g8 = idx & 7;
      const float* src = xbase + (size_t)row * 256 + k0 + g8 * 8;
      float4 a4 = *reinterpret_cast<const float4*>(src);
      float4 b4 = *reinterpret_cast<const float4*>(src + 4);
      short8 v;
      v[0] = (short)f2bf(a4.x); v[1] = (short)f2bf(a4.y); v[2] = (short)f2bf(a4.z); v[3] = (short)f2bf(a4.w);
      v[4] = (short)f2bf(b4.x); v[5] = (short)f2bf(b4.y); v[6] = (short)f2bf(b4.z); v[7] = (short)f2bf(b4.w);
      int byteoff = (row * 128 + g8 * 16) ^ ((row & 7) << 4);
      *reinterpret_cast<short8*>(Al + byteoff) = v;
    }
    __syncthreads();
    #pragma unroll
    for (int ks = 0; ks < 2; ks++) {
      int koff = (ks * 64 + kg * 16) ^ swz;
      short8 af[2], bfr[4];
      #pragma unroll
      for (int mi = 0; mi < 2; mi++)
        af[mi] = *reinterpret_cast<const short8*>(Al + (w * 32 + mi * 16 + l15) * 128 + koff);
      #pragma unroll
      for (int ni = 0; ni < 4; ni++)
        bfr[ni] = *reinterpret_cast<const short8*>(Bl + (ni * 16 + l15) * 128 + koff);
      #pragma unroll
      for (int mi = 0; mi < 2; mi++)
        #pragma unroll
        for (int ni = 0; ni < 4; ni++)
          acc[mi][ni] = __builtin_amdgcn_mfma_f32_16x16x32_bf16(af[mi], bfr[ni], acc[mi][ni], 0, 0, 0);
    }
    __syncthreads();
  }
  // phase 2, split by s-half: QL[64][68] holds one s-row (64 ws) of Q at a time.
  #pragma unroll
  for (int sh = 0; sh < 2; sh++) {
    if ((w >> 1) == sh) {
      #pragma unroll
      for (int ni = 0; ni < 4; ni++) {
        float bqv = bq[d0 + ni * 16 + l15];
        #pragma unroll
        for (int mi = 0; mi < 2; mi++) {
          f32x4 vv = acc[mi][ni];
          int m = (w & 1) * 32 + mi * 16 + kg * 4;  // row within this s-half (0..63)
          #pragma unroll
          for (int j = 0; j < 4; j++)
            QL[(m + j) * 68 + ni * 16 + l15] = vv[j] + bqv;
        }
      }
    }
    __syncthreads();
    // DFT for this s: thread = (d-pair, f2-quad); 2d x 4f2 outputs each
    {
      int dp = tid >> 3, f2q = tid & 7;
      f32x4 a0 = (f32x4){0.f, 0.f, 0.f, 0.f};
      f32x4 a1 = (f32x4){0.f, 0.f, 0.f, 0.f};
      const float* qbase = QL + dp * 2;
      const float* wbase = WL + f2q * 4;
      #pragma unroll 8
      for (int wsx = 0; wsx < 64; wsx++) {
        float2 q = *reinterpret_cast<const float2*>(qbase + wsx * 68);
        f32x4 wv = *reinterpret_cast<const f32x4*>(wbase + wsx * 32);
        a0 += wv * q.x;
        a1 += wv * q.y;
      }
      int sgl = st * 2 + sh;
      size_t g0 = ((size_t)(b * 512 + sgl) * 256 + d0 + dp * 2) * 32 + f2q * 4;
      *reinterpret_cast<f32x4*>(&Fwg[g0]) = a0;
      *reinterpret_cast<f32x4*>(&Fwg[g0 + 32]) = a1;
    }
    if (sh == 0) __syncthreads();  // QL reused by second half
  }
}

// ---------------- K3f: per (b,d): t-DFT + selected hs-reduction, f-SPLIT halves -> X[bd][p][f] ----------------
// LDS 50.3 KB -> 3 blocks/CU (was 82 KB -> 1 block/CU).
__global__ __launch_bounds__(512) void k3f(const float* __restrict__ Fwg, const float* __restrict__ tabp,
                                           const int* __restrict__ panel, float* __restrict__ X) {
  __shared__ float2 Floc[4096];   // 32 KB: [s=512][fh=8] cplx, in-place [kt=16][hs=32][8]
  __shared__ float2 fhT[32][64];  // 16 KB
  __shared__ float2 W16L[16][16]; // 2 KB
  __shared__ int ktl[64];
  int bd = blockIdx.x; int b = bd >> 8; int d = bd & 255;
  int tid = threadIdx.x;
  if (tid < 256) W16L[tid >> 4][tid & 15] = reinterpret_cast<const float2*>(tabp + OFF_W16)[tid];
  for (int i = tid; i < 2048; i += 512) fhT[i >> 6][i & 63] = reinterpret_cast<const float2*>(tabp + OFF_FHT)[i];
  if (tid < 64) ktl[tid] = panel[tid] >> 5;
  #pragma unroll
  for (int fh = 0; fh < 2; fh++) {
    // stage this f-half: 512 rows x 64 B
    {
      const char* gb = (const char*)Fwg;
      #pragma unroll
      for (int r = 0; r < 4; r++) {
        int o = r * 8192 + tid * 16;
        int s = o >> 6; int c16 = (o >> 4) & 3;
        size_t gaddr = ((size_t)(b * 512 + s) * 256 + d) * 128 + (size_t)fh * 64 + (size_t)c16 * 16;
        gl_lds16(gb + gaddr, (char*)Floc + o);
      }
    }
    __syncthreads();
    // t-DFT: thread = (rep, hs, f); column (hs,f) shared by rep-pair -> read all, barrier, write
    int f = tid & 7, hs = (tid >> 3) & 31, rep = tid >> 8;
    float2 v[16];
    #pragma unroll
    for (int t = 0; t < 16; t++) v[t] = Floc[(t * 32 + hs) * 8 + f];
    __syncthreads();  // all reads complete before any writes
    float2 a[8];
    #pragma unroll
    for (int k8 = 0; k8 < 8; k8++) a[k8] = make_float2(0.f, 0.f);
    #pragma unroll
    for (int t = 0; t < 16; t++) {
      float2 vv = v[t];
      #pragma unroll
      for (int k8 = 0; k8 < 8; k8++) {
        float2 w = W16L[t][rep * 8 + k8];
        a[k8].x += w.x * vv.x - w.y * vv.y;
        a[k8].y += w.x * vv.y + w.y * vv.x;
      }
    }
    #pragma unroll
    for (int k8 = 0; k8 < 8; k8++) Floc[((rep * 8 + k8) * 32 + hs) * 8 + f] = a[k8];
    __syncthreads();
    // hs-phase: thread = (p, f)
    {
      int p = tid >> 3, ff = tid & 7;
      int kt = ktl[p];
      float ar = 0.f, ai = 0.f;
      #pragma unroll 8
      for (int h = 0; h < 32; h++) {
        float2 e = fhT[h][p];
        float2 u = Floc[(kt * 32 + h) * 8 + ff];
        ar += u.x * e.x - u.y * e.y;
        ai += u.x * e.y + u.y * e.x;
      }
      reinterpret_cast<float2*>(X)[(size_t)bd * 1024 + p * 16 + fh * 8 + ff] = make_float2(ar, ai);
    }
    if (fh == 0) __syncthreads();  // Floc reused by second half
  }
}

// ---------------- K3b: mode mix out_sel = sum_i x_sel * w ----------------
__global__ __launch_bounds__(512) void k3b_mix(const float* __restrict__ X, const float* __restrict__ wreal,
                                               const float* __restrict__ wimag, float* __restrict__ V) {
  __shared__ float2 xs[4][32][16];
  int h = blockIdx.x >> 6;
  int p = blockIdx.x & 63;
  int tid = threadIdx.x;
  const float2* Xv = reinterpret_cast<const float2*>(X);
  for (int i = tid; i < 2048; i += 512) {
    int b = i >> 9, ii = (i >> 4) & 31, f = i & 15;
    xs[b][ii][f] = Xv[((size_t)(b * 256 + h * 32 + ii) * MP + p) * ML + f];
  }
  __syncthreads();
  int o = tid >> 4, f = tid & 15;
  float accr[4] = {0, 0, 0, 0}, acci[4] = {0, 0, 0, 0};
  for (int i = 0; i < 32; i++) {
    size_t wofs = ((((size_t)h * 32 + i) * 32 + o) * MP + p) * ML + f;
    float wr = wreal[wofs], wi = wimag[wofs];
    #pragma unroll
    for (int b = 0; b < 4; b++) {
      float2 xv = xs[b][i][f];
      accr[b] += xv.x * wr - xv.y * wi;
      acci[b] += xv.x * wi + xv.y * wr;
    }
  }
  #pragma unroll
  for (int b = 0; b < 4; b++)
    reinterpret_cast<float2*>(V)[((size_t)(b * 256 + h * 32 + o) * MP + p) * ML + f] =
        make_float2(accr[b], acci[b]);
}

// ---------------- K4a: inverse spatial DFT -> G[b][c][s][f] (fp32, global) ----------------
__global__ __launch_bounds__(256) void k4a_inv(const float* __restrict__ V, const float* __restrict__ tabp,
                                               float* __restrict__ gbuf) {
  __shared__ float2 vl[64][16];
  __shared__ float2 ft[64][16];
  __shared__ float2 fh[64][32];
  int bd = blockIdx.x;
  int tid = threadIdx.x;
  const float2* Vv = reinterpret_cast<const float2*>(V) + (size_t)bd * MP * ML;
  for (int i = tid; i < 1024; i += 256) {
    vl[i >> 4][i & 15] = Vv[i];
    ft[i >> 4][i & 15] = make_float2(tabp[OFF_FTRE + i], tabp[OFF_FTIM + i]);
  }
  for (int i = tid; i < 2048; i += 256) fh[i >> 5][i & 31] = make_float2(tabp[OFF_FHRE + i], tabp[OFF_FHIM + i]);
  __syncthreads();
  float g0[16], g1[16];
  #pragma unroll
  for (int f = 0; f < 16; f++) { g0[f] = 0.f; g1[f] = 0.f; }
  int s0 = tid * 2;
  int t0 = s0 >> 5, hs0 = s0 & 31;
  int t1 = (s0 + 1) >> 5, hs1 = (s0 + 1) & 31;
  for (int p = 0; p < 64; p++) {
    float2 et0 = ft[p][t0], eh0 = fh[p][hs0];
    float2 et1 = ft[p][t1], eh1 = fh[p][hs1];
    float er0 = et0.x * eh0.x - et0.y * eh0.y;
    float ei0 = et0.x * eh0.y + et0.y * eh0.x;
    float er1 = et1.x * eh1.x - et1.y * eh1.y;
    float ei1 = et1.x * eh1.y + et1.y * eh1.x;
    #pragma unroll
    for (int f = 0; f < 16; f++) {
      float2 v = vl[p][f];
      g0[f] += v.x * er0 + v.y * ei0;
      g1[f] += v.x * er1 + v.y * ei1;
    }
  }
  float4* gb = reinterpret_cast<float4*>(gbuf + (size_t)bd * 8192 + (size_t)s0 * 16);
  #pragma unroll
  for (int q = 0; q < 4; q++)
    gb[q] = make_float4(g0[q * 4] * (1.f / 512.f), g0[q * 4 + 1] * (1.f / 512.f),
                        g0[q * 4 + 2] * (1.f / 512.f), g0[q * 4 + 3] * (1.f / 512.f));
  #pragma unroll
  for (int q = 0; q < 4; q++)
    gb[4 + q] = make_float4(g1[q * 4] * (1.f / 512.f), g1[q * 4 + 1] * (1.f / 512.f),
                            g1[q * 4 + 2] * (1.f / 512.f), g1[q * 4 + 3] * (1.f / 512.f));
}

// ---------------- K4b: o[b][sp][c] bf16 = sum_f G[b][c][s][f] * cw[f][ws] ----------------
__global__ __launch_bounds__(256) void k4b_cos(const float* __restrict__ gbuf, const float* __restrict__ tabp,
                                               unsigned short* __restrict__ ob) {
  __shared__ float Gs[256][17];
  __shared__ float cwL[16][64];
  int s = blockIdx.x, b = blockIdx.y;
  int tid = threadIdx.x;
  for (int i = tid; i < 4096; i += 256) {
    int c = i >> 4, f = i & 15;
    Gs[c][f] = gbuf[(size_t)(b * 256 + c) * 8192 + s * 16 + f];
  }
  for (int i = tid; i < 1024; i += 256) cwL[i >> 6][i & 63] = tabp[OFF_CW + i];
  __syncthreads();
  int c0 = (tid & 63) * 4, wsg = tid >> 6;
  float gv[4][16];
  #pragma unroll
  for (int j = 0; j < 4; j++)
    #pragma unroll
    for (int f = 0; f < 16; f++) gv[j][f] = Gs[c0 + j][f];
  for (int wsi = 0; wsi < 16; wsi++) {
    int wsx = wsg * 16 + wsi;
    float a0 = 0.f, a1 = 0.f, a2 = 0.f, a3 = 0.f;
    #pragma unroll
    for (int f = 0; f < 16; f++) {
      float cwv = cwL[f][wsx];
      a0 += gv[0][f] * cwv; a1 += gv[1][f] * cwv; a2 += gv[2][f] * cwv; a3 += gv[3][f] * cwv;
    }
    ushort4 u;
    u.x = f2bf(a0); u.y = f2bf(a1); u.z = f2bf(a2); u.w = f2bf(a3);
    *reinterpret_cast<ushort4*>(&ob[((size_t)b * SPAT + (size_t)s * 64 + wsx) * 256 + c0]) = u;
  }
}

// ---------------- K5: out = o @ Wo + bo via bf16 MFMA, out fp32 [b][sp][d] ----------------
__global__ __launch_bounds__(256) void k5_mfma(const unsigned short* __restrict__ ob,
                                               const unsigned short* __restrict__ wot,
                                               const float* __restrict__ bo, float* __restrict__ out) {
  __shared__ char smem[34816];
  unsigned short* Al = (unsigned short*)smem;           // 16384 B
  unsigned short* Bl = (unsigned short*)(smem + 16384); // 8192 B
  float* OL = (float*)smem;                             // [128][68] fp32 epilogue overlay
  int tile, dg;
  xcd_tile_dg(blockIdx.x, tile, dg);
  int b = tile >> 8, sp0 = (tile & 255) << 7, d0 = dg << 6;
  int tid = threadIdx.x;
  int lane = tid & 63, w = tid >> 6;
  int l15 = lane & 15, kg = lane >> 4;
  int swz = (l15 & 7) << 4;
  f32x4 acc[2][4];
  #pragma unroll
  for (int mi = 0; mi < 2; mi++)
    #pragma unroll
    for (int ni = 0; ni < 4; ni++) acc[mi][ni] = (f32x4){0.f, 0.f, 0.f, 0.f};
  const char* Abase = (const char*)(ob + ((size_t)b * 32768 + sp0) * 256);
  const char* Bbase = (const char*)(wot + (size_t)d0 * 256);
  for (int k0 = 0; k0 < 256; k0 += 64) {
    #pragma unroll
    for (int it = 0; it < 2; it++) {
      int o = tid * 16 + it * 4096 + 16384;  // Bl region
      int ol = o - 16384;
      int row = ol >> 7, cb = ol & 127;
      int scb = cb ^ ((row & 7) << 4);
      gl_lds16(Bbase + (size_t)row * 512 + k0 * 2 + scb, smem + o);
    }
    #pragma unroll
    for (int it = 0; it < 4; it++) {
      int o = tid * 16 + it * 4096;
      int row = o >> 7, cb = o & 127;
      int scb = cb ^ ((row & 7) << 4);
      gl_lds16(Abase + (size_t)row * 512 + k0 * 2 + scb, (char*)Al + o);
    }
    __syncthreads();
    #pragma unroll
    for (int ks = 0; ks < 2; ks++) {
      int koff = (ks * 64 + kg * 16) ^ swz;
      short8 af[2], bfr[4];
      #pragma unroll
      for (int mi = 0; mi < 2; mi++)
        af[mi] = *(const short8*)((const char*)Al + (w * 32 + mi * 16 + l15) * 128 + koff);
      #pragma unroll
      for (int ni = 0; ni < 4; ni++)
        bfr[ni] = *(const short8*)((const char*)Bl + (ni * 16 + l15) * 128 + koff);
      #pragma unroll
      for (int mi = 0; mi < 2; mi++)
        #pragma unroll
        for (int ni = 0; ni < 4; ni++)
          acc[mi][ni] = __builtin_amdgcn_mfma_f32_16x16x32_bf16(af[mi], bfr[ni], acc[mi][ni], 0, 0, 0);
    }
    __syncthreads();
  }
  // epilogue via LDS for coalesced 256B stores
  #pragma unroll
  for (int ni = 0; ni < 4; ni++) {
    float bov = bo[d0 + ni * 16 + l15];
    #pragma unroll
    for (int mi = 0; mi < 2; mi++) {
      f32x4 v = acc[mi][ni];
      int m = w * 32 + mi * 16 + kg * 4;
      #pragma unroll
      for (int j = 0; j < 4; j++)
        OL[(m + j) * 68 + ni * 16 + l15] = v[j] + bov;
    }
  }
  __syncthreads();
  int f4 = tid & 15, r0 = tid >> 4;
  #pragma unroll
  for (int r = 0; r < 8; r++) {
    int m = r * 16 + r0;
    float4 val = *reinterpret_cast<const float4*>(&OL[m * 68 + f4 * 4]);
    *reinterpret_cast<float4*>(&out[((size_t)b * SPAT + sp0 + m) * 256 + d0 + f4 * 4]) = val;
  }
}

extern "C" void kernel_launch(void* const* d_in, const int* in_sizes, int n_in,
                              void* d_out, int out_size, void* d_ws, size_t ws_size,
                              hipStream_t stream) {
  const float* x  = (const float*)d_in[0];
  const float* Wq = (const float*)d_in[1];
  const float* bq = (const float*)d_in[2];
  // d_in[3..6] = Wk,bk,Wv,bv -- dead in the reference, skipped
  const float* Wo = (const float*)d_in[7];
  const float* bo = (const float*)d_in[8];
  const float* wr = (const float*)d_in[9];
  const float* wi = (const float*)d_in[10];
  const int* panel = (const int*)d_in[11];
  float* wsf = (float*)d_ws;
  float* out = (float*)d_out;

  float*          gbuf = wsf + OFF_GB;
  unsigned short* obb  = (unsigned short*)(wsf + OFF_FW);  // FW region dead after k3f
  unsigned short* wqt  = (unsigned short*)(wsf + OFF_WT);
  unsigned short* wot  = wqt + 65536;

  k0_tables<<<dim3(1), dim3(256), 0, stream>>>(panel, wsf);
  conv_w<<<dim3(8, 8, 2), dim3(256), 0, stream>>>(Wq, Wo, wqt, wot);
  k1f3<<<dim3(4096), dim3(256), 0, stream>>>(x, wqt, bq, wsf, wsf + OFF_FW);
  k3f<<<dim3(1024), dim3(512), 0, stream>>>(wsf + OFF_FW, wsf, panel, wsf + OFF_X);
  k3b_mix<<<dim3(512), dim3(512), 0, stream>>>(wsf + OFF_X, wr, wi, wsf + OFF_V);
  k4a_inv<<<dim3(1024), dim3(256), 0, stream>>>(wsf + OFF_V, wsf, gbuf);
  k4b_cos<<<dim3(512, 4), dim3(256), 0, stream>>>(gbuf, wsf, obb);
  k5_mfma<<<dim3(4096), dim3(256), 0, stream>>>(obb, wot, bo, out);
}

// Round 15
// 335.757 us; speedup vs baseline: 1.2641x; 1.2641x over previous
//
#include <hip/hip_runtime.h>
#include <hip/hip_bf16.h>
#include <cmath>

// Problem constants
#define BB 4
#define TT 16
#define HH 32
#define WW 64
#define DD 256
#define NHEAD 8
#define EE 32
#define MP 64      // M_PANEL
#define ML 16      // M_LAST
#define SPAT 32768 // TT*HH*WW
#define S2D 512    // TT*HH

// d_ws layout (float offsets)
constexpr size_t OFF_FTRE = 0;        // [p][t] 64x16
constexpr size_t OFF_FTIM = 1024;
constexpr size_t OFF_FHRE = 2048;     // [p][hs] 64x32
constexpr size_t OFF_FHIM = 4096;
constexpr size_t OFF_CW   = 6144;     // [f][ws] 16x64
constexpr size_t OFF_W64I = 7168;     // [ws][f2] 64x32 interleaved re,im
constexpr size_t OFF_W16  = 9216;     // [t][kt] float2 16x16
constexpr size_t OFF_FHT  = 9728;     // [hs][p] float2 32x64
constexpr size_t OFF_GB   = 16384;                 // gbuf fp32 [b][c][s][f] 8.4M floats
constexpr size_t OFF_FW   = OFF_GB + 8388608;      // Fw fp32 [b][s][d][f2] 16.8M floats; after k3f reused: ob bf16
constexpr size_t OFF_X    = OFF_FW + 16777216;     // [bd][p][f] cplx 2.1M floats
constexpr size_t OFF_V    = OFF_X + 2097152;       // [bd][p][f] cplx 2.1M floats
constexpr size_t OFF_WT   = OFF_V + 2097152;       // WqT bf16 65536 + WoT bf16 65536

typedef short short8 __attribute__((ext_vector_type(8)));
typedef float f32x4 __attribute__((ext_vector_type(4)));

static __device__ __forceinline__ unsigned short f2bf(float x) {
  union { float f; unsigned u; } v; v.f = x;
  unsigned r = v.u + 0x7fffu + ((v.u >> 16) & 1u);
  return (unsigned short)(r >> 16);
}

static __device__ __forceinline__ void gl_lds16(const void* g, void* l) {
  __builtin_amdgcn_global_load_lds((const __attribute__((address_space(1))) void*)g,
                                   (__attribute__((address_space(3))) void*)l, 16, 0, 0);
}

// XCD-pinning bijective swizzle for 4-sibling tiles: flat in [0,4096) ->
// tile in [0,1024), dg in [0,4) with all 4 dg of a tile on the same XCD (flat%8).
static __device__ __forceinline__ void xcd_tile_dg(int flat, int& tile, int& dg) {
  int w8 = flat >> 3, xl = flat & 7;
  tile = ((w8 >> 2) << 3) | xl;
  dg = w8 & 3;
}

// ---------------- K0: twiddle tables ----------------
__global__ __launch_bounds__(256) void k0_tables(const int* __restrict__ panel, float* __restrict__ tab) {
  __shared__ int kt[MP], kh[MP];
  int tid = threadIdx.x;
  if (tid < MP) { int s = panel[tid]; kt[tid] = s >> 5; kh[tid] = s & 31; }
  __syncthreads();
  const double PI2 = 6.283185307179586476925286766559;
  for (int i = tid; i < 1024; i += 256) {  // FT [p][t]
    int p = i >> 4, t = i & 15;
    double a = -PI2 * (double)((t * kt[p]) & 15) / 16.0;
    tab[OFF_FTRE + i] = (float)cos(a);
    tab[OFF_FTIM + i] = (float)sin(a);
  }
  for (int i = tid; i < 2048; i += 256) {  // FH [p][hs]
    int p = i >> 5, hs = i & 31;
    double a = -PI2 * (double)((hs * kh[p]) & 31) / 32.0;
    tab[OFF_FHRE + i] = (float)cos(a);
    tab[OFF_FHIM + i] = (float)sin(a);
  }
  for (int i = tid; i < 1024; i += 256) {  // CW [f][ws]
    int f = i >> 6, wsx = i & 63;
    double a = PI2 * (double)((f * wsx) & 63) / 64.0;
    tab[OFF_CW + i] = (f == 0) ? (1.0f / 64.0f) : (float)(2.0 * cos(a) / 64.0);
  }
  for (int i = tid; i < 2048; i += 256) {  // W64I [ws][f2]
    int wsx = i >> 5, f2 = i & 31; int f = f2 >> 1;
    double a = -PI2 * (double)((wsx * f) & 63) / 64.0;
    tab[OFF_W64I + i] = (f2 & 1) ? (float)sin(a) : (float)cos(a);
  }
  if (tid < 256) {                         // W16 [t][kt] float2
    int t = tid >> 4, k = tid & 15;
    double a = -PI2 * (double)((t * k) & 15) / 16.0;
    tab[OFF_W16 + 2 * tid]     = (float)cos(a);
    tab[OFF_W16 + 2 * tid + 1] = (float)sin(a);
  }
  for (int i = tid; i < 2048; i += 256) {  // FHT [hs][p] float2
    int hs = i >> 6, p = i & 63;
    double a = -PI2 * (double)((hs * kh[p]) & 31) / 32.0;
    tab[OFF_FHT + 2 * i]     = (float)cos(a);
    tab[OFF_FHT + 2 * i + 1] = (float)sin(a);
  }
}

// ---------------- conv_w: Wq/Wo fp32 [k][d] -> WT bf16 [d][k] ----------------
__global__ __launch_bounds__(256) void conv_w(const float* __restrict__ Wq, const float* __restrict__ Wo,
                                              unsigned short* __restrict__ wqt, unsigned short* __restrict__ wot) {
  __shared__ float tile[32][33];
  const float* src = blockIdx.z ? Wo : Wq;
  unsigned short* dst = blockIdx.z ? wot : wqt;
  int k0 = blockIdx.x * 32, d0 = blockIdx.y * 32;
  int tx = threadIdx.x & 31, r4 = threadIdx.x >> 5;
  #pragma unroll
  for (int it = 0; it < 4; it++) {
    int row = r4 + it * 8;
    tile[row][tx] = src[(size_t)(k0 + row) * 256 + d0 + tx];
  }
  __syncthreads();
  #pragma unroll
  for (int it = 0; it < 4; it++) {
    int row = r4 + it * 8;
    dst[(size_t)(d0 + row) * 256 + k0 + tx] = f2bf(tile[tx][row]);
  }
}

// ---------------- K1f3: Q=x@Wq+bq (bf16 MFMA) + reg-tiled ws-DFT (s-split) -> Fw[b][s][d][f2] ----------------
// Flat grid 4096, XCD-pinned siblings. LDS 32.75 KB. (round-12 proven version)
__global__ __launch_bounds__(256) void k1f3(const float* __restrict__ x,
                                            const unsigned short* __restrict__ wqt,
                                            const float* __restrict__ bq,
                                            const float* __restrict__ tabp,
                                            float* __restrict__ Fwg) {
  __shared__ char smem[32768];
  char*  Al = smem;                      // [128 sp][128 B] bf16, XOR-swizzled (16384 B)
  char*  Bl = smem + 16384;              // [64 d][128 B] bf16, XOR-swizzled (8192 B)
  float* QL = (float*)smem;              // [64][68] fp32 overlay of Al+Bl (17408 B <= 24576)
  float* WL = (float*)(smem + 24576);    // [64 ws][32 f2] fp32 (8192 B, persistent)
  int tile, dg;
  xcd_tile_dg(blockIdx.x, tile, dg);
  int d0 = dg << 6;
  int b = tile >> 8, st = tile & 255;
  int sp0 = st << 7;
  int tid = threadIdx.x;
  int lane = tid & 63, w = tid >> 6;
  int l15 = lane & 15, kg = lane >> 4;
  int swz = (l15 & 7) << 4;
  for (int i = tid; i < 2048; i += 256) WL[i] = tabp[OFF_W64I + i];
  f32x4 acc[2][4];
  #pragma unroll
  for (int mi = 0; mi < 2; mi++)
    #pragma unroll
    for (int ni = 0; ni < 4; ni++) acc[mi][ni] = (f32x4){0.f, 0.f, 0.f, 0.f};
  const float* xbase = x + ((size_t)b * 32768 + sp0) * 256;
  const char* Bbase = (const char*)(wqt + (size_t)d0 * 256);
  for (int k0 = 0; k0 < 256; k0 += 64) {
    // B-stage first: async gl_lds in flight during the A convert below
    #pragma unroll
    for (int it = 0; it < 2; it++) {
      int o = it * 4096 + tid * 16;
      int row = o >> 7, cb = o & 127;
      gl_lds16(Bbase + (size_t)row * 512 + k0 * 2 + (cb ^ ((row & 7) << 4)), Bl + o);
    }
    // A-stage: x fp32 -> bf16 -> swizzled LDS (in-register convert)
    #pragma unroll
    for (int it = 0; it < 4; it++) {
      int idx = it * 256 + tid;
      int row = idx >> 3, g8 = idx & 7;
      const float* src = xbase + (size_t)row * 256 + k0 + g8 * 8;
      float4 a4 = *reinterpret_cast<const float4*>(src);
      float4 b4 = *reinterpret_cast<const float4*>(src + 4);
      short8 v;
      v[0] = (short)f2bf(a4.x); v[1] = (short)f2bf(a4.y); v[2] = (short)f2bf(a4.z); v[3] = (short)f2bf(a4.w);
      v[4] = (short)f2bf(b4.x); v[5] = (short)f2bf(b4.y); v[6] = (short)f2bf(b4.z); v[7] = (short)f2bf(b4.w);
      int byteoff = (row * 128 + g8 * 16) ^ ((row & 7) << 4);
      *reinterpret_cast<short8*>(Al + byteoff) = v;
    }
    __syncthreads();
    #pragma unroll
    for (int ks = 0; ks < 2; ks++) {
      int koff = (ks * 64 + kg * 16) ^ swz;
      short8 af[2], bfr[4];
      #pragma unroll
      for (int mi = 0; mi < 2; mi++)
        af[mi] = *reinterpret_cast<const short8*>(Al + (w * 32 + mi * 16 + l15) * 128 + koff);
      #pragma unroll
      for (int ni = 0; ni < 4; ni++)
        bfr[ni] = *reinterpret_cast<const short8*>(Bl + (ni * 16 + l15) * 128 + koff);
      #pragma unroll
      for (int mi = 0; mi < 2; mi++)
        #pragma unroll
        for (int ni = 0; ni < 4; ni++)
          acc[mi][ni] = __builtin_amdgcn_mfma_f32_16x16x32_bf16(af[mi], bfr[ni], acc[mi][ni], 0, 0, 0);
    }
    __syncthreads();
  }
  // phase 2, split by s-half: QL[64][68] holds one s-row (64 ws) of Q at a time.
  #pragma unroll
  for (int sh = 0; sh < 2; sh++) {
    if ((w >> 1) == sh) {
      #pragma unroll
      for (int ni = 0; ni < 4; ni++) {
        float bqv = bq[d0 + ni * 16 + l15];
        #pragma unroll
        for (int mi = 0; mi < 2; mi++) {
          f32x4 vv = acc[mi][ni];
          int m = (w & 1) * 32 + mi * 16 + kg * 4;  // row within this s-half (0..63)
          #pragma unroll
          for (int j = 0; j < 4; j++)
            QL[(m + j) * 68 + ni * 16 + l15] = vv[j] + bqv;
        }
      }
    }
    __syncthreads();
    // DFT for this s: thread = (d-pair, f2-quad); 2d x 4f2 outputs each
    {
      int dp = tid >> 3, f2q = tid & 7;
      f32x4 a0 = (f32x4){0.f, 0.f, 0.f, 0.f};
      f32x4 a1 = (f32x4){0.f, 0.f, 0.f, 0.f};
      const float* qbase = QL + dp * 2;
      const float* wbase = WL + f2q * 4;
      #pragma unroll 8
      for (int wsx = 0; wsx < 64; wsx++) {
        float2 q = *reinterpret_cast<const float2*>(qbase + wsx * 68);
        f32x4 wv = *reinterpret_cast<const f32x4*>(wbase + wsx * 32);
        a0 += wv * q.x;
        a1 += wv * q.y;
      }
      int sgl = st * 2 + sh;
      size_t g0 = ((size_t)(b * 512 + sgl) * 256 + d0 + dp * 2) * 32 + f2q * 4;
      *reinterpret_cast<f32x4*>(&Fwg[g0]) = a0;
      *reinterpret_cast<f32x4*>(&Fwg[g0 + 32]) = a1;
    }
    if (sh == 0) __syncthreads();  // QL reused by second half
  }
}

// ---------------- K3f: per (b,d): t-DFT (in-place LDS) + selected hs-reduction -> X[bd][p][f] ----------------
// (round-12 proven single-pass version, 82 KB LDS)
__global__ __launch_bounds__(512) void k3f(const float* __restrict__ Fwg, const float* __restrict__ tabp,
                                           const int* __restrict__ panel, float* __restrict__ X) {
  __shared__ float2 Floc[8192];   // 64 KB
  __shared__ float2 fhT[32][64];  // 16 KB
  __shared__ float2 W16L[16][16]; // 2 KB
  __shared__ int ktl[64];
  int bd = blockIdx.x; int b = bd >> 8; int d = bd & 255;
  int tid = threadIdx.x;
  if (tid < 256) W16L[tid >> 4][tid & 15] = reinterpret_cast<const float2*>(tabp + OFF_W16)[tid];
  for (int i = tid; i < 2048; i += 512) fhT[i >> 6][i & 63] = reinterpret_cast<const float2*>(tabp + OFF_FHT)[i];
  if (tid < 64) ktl[tid] = panel[tid] >> 5;
  {
    const char* gb = (const char*)Fwg;
    #pragma unroll
    for (int r = 0; r < 8; r++) {
      int o = r * 8192 + tid * 16;
      int s = o >> 7; int c16 = (o >> 4) & 7;
      size_t gaddr = ((size_t)(b * 512 + s) * 256 + d) * 128 + (size_t)c16 * 16;
      gl_lds16(gb + gaddr, (char*)Floc + o);
    }
  }
  __syncthreads();
  int hs = tid >> 4, f = tid & 15;
  float2 v[16];
  #pragma unroll
  for (int t = 0; t < 16; t++) v[t] = Floc[(t * 32 + hs) * 16 + f];
  float2 a[16];
  #pragma unroll
  for (int k = 0; k < 16; k++) a[k] = make_float2(0.f, 0.f);
  #pragma unroll
  for (int t = 0; t < 16; t++) {
    float2 vv = v[t];
    #pragma unroll
    for (int k = 0; k < 16; k++) {
      float2 w = W16L[t][k];
      a[k].x += w.x * vv.x - w.y * vv.y;
      a[k].y += w.x * vv.y + w.y * vv.x;
    }
  }
  #pragma unroll
  for (int k = 0; k < 16; k++) Floc[(k * 32 + hs) * 16 + f] = a[k];
  __syncthreads();
  int p2 = tid >> 4;
  float2 res[2];
  #pragma unroll
  for (int half = 0; half < 2; half++) {
    int p = p2 + half * 32;
    int kt = ktl[p];
    float ar = 0.f, ai = 0.f;
    #pragma unroll 8
    for (int h = 0; h < 32; h++) {
      float2 e = fhT[h][p];
      float2 u = Floc[(kt * 32 + h) * 16 + f];
      ar += u.x * e.x - u.y * e.y;
      ai += u.x * e.y + u.y * e.x;
    }
    res[half] = make_float2(ar, ai);
  }
  float2* Xo = reinterpret_cast<float2*>(X) + (size_t)bd * 1024;
  Xo[p2 * 16 + f] = res[0];
  Xo[(p2 + 32) * 16 + f] = res[1];
}

// ---------------- K3b: mode mix out_sel = sum_i x_sel * w ----------------
__global__ __launch_bounds__(512) void k3b_mix(const float* __restrict__ X, const float* __restrict__ wreal,
                                               const float* __restrict__ wimag, float* __restrict__ V) {
  __shared__ float2 xs[4][32][16];
  int h = blockIdx.x >> 6;
  int p = blockIdx.x & 63;
  int tid = threadIdx.x;
  const float2* Xv = reinterpret_cast<const float2*>(X);
  for (int i = tid; i < 2048; i += 512) {
    int b = i >> 9, ii = (i >> 4) & 31, f = i & 15;
    xs[b][ii][f] = Xv[((size_t)(b * 256 + h * 32 + ii) * MP + p) * ML + f];
  }
  __syncthreads();
  int o = tid >> 4, f = tid & 15;
  float accr[4] = {0, 0, 0, 0}, acci[4] = {0, 0, 0, 0};
  for (int i = 0; i < 32; i++) {
    size_t wofs = ((((size_t)h * 32 + i) * 32 + o) * MP + p) * ML + f;
    float wr = wreal[wofs], wi = wimag[wofs];
    #pragma unroll
    for (int b = 0; b < 4; b++) {
      float2 xv = xs[b][i][f];
      accr[b] += xv.x * wr - xv.y * wi;
      acci[b] += xv.x * wi + xv.y * wr;
    }
  }
  #pragma unroll
  for (int b = 0; b < 4; b++)
    reinterpret_cast<float2*>(V)[((size_t)(b * 256 + h * 32 + o) * MP + p) * ML + f] =
        make_float2(accr[b], acci[b]);
}

// ---------------- K4a: inverse spatial DFT -> G[b][c][s][f] (fp32, global) ----------------
__global__ __launch_bounds__(256) void k4a_inv(const float* __restrict__ V, const float* __restrict__ tabp,
                                               float* __restrict__ gbuf) {
  __shared__ float2 vl[64][16];
  __shared__ float2 ft[64][16];
  __shared__ float2 fh[64][32];
  int bd = blockIdx.x;
  int tid = threadIdx.x;
  const float2* Vv = reinterpret_cast<const float2*>(V) + (size_t)bd * MP * ML;
  for (int i = tid; i < 1024; i += 256) {
    vl[i >> 4][i & 15] = Vv[i];
    ft[i >> 4][i & 15] = make_float2(tabp[OFF_FTRE + i], tabp[OFF_FTIM + i]);
  }
  for (int i = tid; i < 2048; i += 256) fh[i >> 5][i & 31] = make_float2(tabp[OFF_FHRE + i], tabp[OFF_FHIM + i]);
  __syncthreads();
  float g0[16], g1[16];
  #pragma unroll
  for (int f = 0; f < 16; f++) { g0[f] = 0.f; g1[f] = 0.f; }
  int s0 = tid * 2;
  int t0 = s0 >> 5, hs0 = s0 & 31;
  int t1 = (s0 + 1) >> 5, hs1 = (s0 + 1) & 31;
  for (int p = 0; p < 64; p++) {
    float2 et0 = ft[p][t0], eh0 = fh[p][hs0];
    float2 et1 = ft[p][t1], eh1 = fh[p][hs1];
    float er0 = et0.x * eh0.x - et0.y * eh0.y;
    float ei0 = et0.x * eh0.y + et0.y * eh0.x;
    float er1 = et1.x * eh1.x - et1.y * eh1.y;
    float ei1 = et1.x * eh1.y + et1.y * eh1.x;
    #pragma unroll
    for (int f = 0; f < 16; f++) {
      float2 v = vl[p][f];
      g0[f] += v.x * er0 + v.y * ei0;
      g1[f] += v.x * er1 + v.y * ei1;
    }
  }
  float4* gb = reinterpret_cast<float4*>(gbuf + (size_t)bd * 8192 + (size_t)s0 * 16);
  #pragma unroll
  for (int q = 0; q < 4; q++)
    gb[q] = make_float4(g0[q * 4] * (1.f / 512.f), g0[q * 4 + 1] * (1.f / 512.f),
                        g0[q * 4 + 2] * (1.f / 512.f), g0[q * 4 + 3] * (1.f / 512.f));
  #pragma unroll
  for (int q = 0; q < 4; q++)
    gb[4 + q] = make_float4(g1[q * 4] * (1.f / 512.f), g1[q * 4 + 1] * (1.f / 512.f),
                            g1[q * 4 + 2] * (1.f / 512.f), g1[q * 4 + 3] * (1.f / 512.f));
}

// ---------------- K4b: o[b][sp][c] bf16 = sum_f G[b][c][s][f] * cw[f][ws] ----------------
__global__ __launch_bounds__(256) void k4b_cos(const float* __restrict__ gbuf, const float* __restrict__ tabp,
                                               unsigned short* __restrict__ ob) {
  __shared__ float Gs[256][17];
  __shared__ float cwL[16][64];
  int s = blockIdx.x, b = blockIdx.y;
  int tid = threadIdx.x;
  for (int i = tid; i < 4096; i += 256) {
    int c = i >> 4, f = i & 15;
    Gs[c][f] = gbuf[(size_t)(b * 256 + c) * 8192 + s * 16 + f];
  }
  for (int i = tid; i < 1024; i += 256) cwL[i >> 6][i & 63] = tabp[OFF_CW + i];
  __syncthreads();
  int c0 = (tid & 63) * 4, wsg = tid >> 6;
  float gv[4][16];
  #pragma unroll
  for (int j = 0; j < 4; j++)
    #pragma unroll
    for (int f = 0; f < 16; f++) gv[j][f] = Gs[c0 + j][f];
  for (int wsi = 0; wsi < 16; wsi++) {
    int wsx = wsg * 16 + wsi;
    float a0 = 0.f, a1 = 0.f, a2 = 0.f, a3 = 0.f;
    #pragma unroll
    for (int f = 0; f < 16; f++) {
      float cwv = cwL[f][wsx];
      a0 += gv[0][f] * cwv; a1 += gv[1][f] * cwv; a2 += gv[2][f] * cwv; a3 += gv[3][f] * cwv;
    }
    ushort4 u;
    u.x = f2bf(a0); u.y = f2bf(a1); u.z = f2bf(a2); u.w = f2bf(a3);
    *reinterpret_cast<ushort4*>(&ob[((size_t)b * SPAT + (size_t)s * 64 + wsx) * 256 + c0]) = u;
  }
}

// ---------------- K5: out = o @ Wo + bo via bf16 MFMA, out fp32 [b][sp][d] ----------------
__global__ __launch_bounds__(256) void k5_mfma(const unsigned short* __restrict__ ob,
                                               const unsigned short* __restrict__ wot,
                                               const float* __restrict__ bo, float* __restrict__ out) {
  __shared__ char smem[34816];
  unsigned short* Al = (unsigned short*)smem;           // 16384 B
  unsigned short* Bl = (unsigned short*)(smem + 16384); // 8192 B
  float* OL = (float*)smem;                             // [128][68] fp32 epilogue overlay
  int tile, dg;
  xcd_tile_dg(blockIdx.x, tile, dg);
  int b = tile >> 8, sp0 = (tile & 255) << 7, d0 = dg << 6;
  int tid = threadIdx.x;
  int lane = tid & 63, w = tid >> 6;
  int l15 = lane & 15, kg = lane >> 4;
  int swz = (l15 & 7) << 4;
  f32x4 acc[2][4];
  #pragma unroll
  for (int mi = 0; mi < 2; mi++)
    #pragma unroll
    for (int ni = 0; ni < 4; ni++) acc[mi][ni] = (f32x4){0.f, 0.f, 0.f, 0.f};
  const char* Abase = (const char*)(ob + ((size_t)b * 32768 + sp0) * 256);
  const char* Bbase = (const char*)(wot + (size_t)d0 * 256);
  for (int k0 = 0; k0 < 256; k0 += 64) {
    #pragma unroll
    for (int it = 0; it < 2; it++) {
      int o = tid * 16 + it * 4096 + 16384;  // Bl region
      int ol = o - 16384;
      int row = ol >> 7, cb = ol & 127;
      int scb = cb ^ ((row & 7) << 4);
      gl_lds16(Bbase + (size_t)row * 512 + k0 * 2 + scb, smem + o);
    }
    #pragma unroll
    for (int it = 0; it < 4; it++) {
      int o = tid * 16 + it * 4096;
      int row = o >> 7, cb = o & 127;
      int scb = cb ^ ((row & 7) << 4);
      gl_lds16(Abase + (size_t)row * 512 + k0 * 2 + scb, (char*)Al + o);
    }
    __syncthreads();
    #pragma unroll
    for (int ks = 0; ks < 2; ks++) {
      int koff = (ks * 64 + kg * 16) ^ swz;
      short8 af[2], bfr[4];
      #pragma unroll
      for (int mi = 0; mi < 2; mi++)
        af[mi] = *(const short8*)((const char*)Al + (w * 32 + mi * 16 + l15) * 128 + koff);
      #pragma unroll
      for (int ni = 0; ni < 4; ni++)
        bfr[ni] = *(const short8*)((const char*)Bl + (ni * 16 + l15) * 128 + koff);
      #pragma unroll
      for (int mi = 0; mi < 2; mi++)
        #pragma unroll
        for (int ni = 0; ni < 4; ni++)
          acc[mi][ni] = __builtin_amdgcn_mfma_f32_16x16x32_bf16(af[mi], bfr[ni], acc[mi][ni], 0, 0, 0);
    }
    __syncthreads();
  }
  // epilogue via LDS for coalesced 256B stores
  #pragma unroll
  for (int ni = 0; ni < 4; ni++) {
    float bov = bo[d0 + ni * 16 + l15];
    #pragma unroll
    for (int mi = 0; mi < 2; mi++) {
      f32x4 v = acc[mi][ni];
      int m = w * 32 + mi * 16 + kg * 4;
      #pragma unroll
      for (int j = 0; j < 4; j++)
        OL[(m + j) * 68 + ni * 16 + l15] = v[j] + bov;
    }
  }
  __syncthreads();
  int f4 = tid & 15, r0 = tid >> 4;
  #pragma unroll
  for (int r = 0; r < 8; r++) {
    int m = r * 16 + r0;
    float4 val = *reinterpret_cast<const float4*>(&OL[m * 68 + f4 * 4]);
    *reinterpret_cast<float4*>(&out[((size_t)b * SPAT + sp0 + m) * 256 + d0 + f4 * 4]) = val;
  }
}

extern "C" void kernel_launch(void* const* d_in, const int* in_sizes, int n_in,
                              void* d_out, int out_size, void* d_ws, size_t ws_size,
                              hipStream_t stream) {
  const float* x  = (const float*)d_in[0];
  const float* Wq = (const float*)d_in[1];
  const float* bq = (const float*)d_in[2];
  // d_in[3..6] = Wk,bk,Wv,bv -- dead in the reference, skipped
  const float* Wo = (const float*)d_in[7];
  const float* bo = (const float*)d_in[8];
  const float* wr = (const float*)d_in[9];
  const float* wi = (const float*)d_in[10];
  const int* panel = (const int*)d_in[11];
  float* wsf = (float*)d_ws;
  float* out = (float*)d_out;

  float*          gbuf = wsf + OFF_GB;
  unsigned short* obb  = (unsigned short*)(wsf + OFF_FW);  // FW region dead after k3f
  unsigned short* wqt  = (unsigned short*)(wsf + OFF_WT);
  unsigned short* wot  = wqt + 65536;

  k0_tables<<<dim3(1), dim3(256), 0, stream>>>(panel, wsf);
  conv_w<<<dim3(8, 8, 2), dim3(256), 0, stream>>>(Wq, Wo, wqt, wot);
  k1f3<<<dim3(4096), dim3(256), 0, stream>>>(x, wqt, bq, wsf, wsf + OFF_FW);
  k3f<<<dim3(1024), dim3(512), 0, stream>>>(wsf + OFF_FW, wsf, panel, wsf + OFF_X);
  k3b_mix<<<dim3(512), dim3(512), 0, stream>>>(wsf + OFF_X, wr, wi, wsf + OFF_V);
  k4a_inv<<<dim3(1024), dim3(256), 0, stream>>>(wsf + OFF_V, wsf, gbuf);
  k4b_cos<<<dim3(512, 4), dim3(256), 0, stream>>>(gbuf, wsf, obb);
  k5_mfma<<<dim3(4096), dim3(256), 0, stream>>>(obb, wot, bo, out);
}

// Round 16
// 330.027 us; speedup vs baseline: 1.2860x; 1.0174x over previous
//
#include <hip/hip_runtime.h>
#include <hip/hip_bf16.h>
#include <cmath>

// Problem constants
#define BB 4
#define TT 16
#define HH 32
#define WW 64
#define DD 256
#define NHEAD 8
#define EE 32
#define MP 64      // M_PANEL
#define ML 16      // M_LAST
#define SPAT 32768 // TT*HH*WW
#define S2D 512    // TT*HH

// d_ws layout (float offsets)
constexpr size_t OFF_FTRE = 0;        // [p][t] 64x16
constexpr size_t OFF_FTIM = 1024;
constexpr size_t OFF_FHRE = 2048;     // [p][hs] 64x32
constexpr size_t OFF_FHIM = 4096;
constexpr size_t OFF_CW   = 6144;     // [f][ws] 16x64
constexpr size_t OFF_W64I = 7168;     // [ws][f2] 64x32 interleaved re,im
constexpr size_t OFF_W16  = 9216;     // [t][kt] float2 16x16
constexpr size_t OFF_FHT  = 9728;     // [hs][p] float2 32x64
constexpr size_t OFF_GB   = 16384;                 // gbuf fp32 [b][c][s][f] 8.4M floats
constexpr size_t OFF_FW   = OFF_GB + 8388608;      // Fw fp32 [b][s][d][f2] 16.8M floats; after k3f reused: ob bf16
constexpr size_t OFF_X    = OFF_FW + 16777216;     // [bd][p][f] cplx 2.1M floats
constexpr size_t OFF_V    = OFF_X + 2097152;       // [bd][p][f] cplx 2.1M floats
constexpr size_t OFF_WT   = OFF_V + 2097152;       // WqT bf16 65536 + WoT bf16 65536

typedef short short8 __attribute__((ext_vector_type(8)));
typedef float f32x4 __attribute__((ext_vector_type(4)));

static __device__ __forceinline__ unsigned short f2bf(float x) {
  union { float f; unsigned u; } v; v.f = x;
  unsigned r = v.u + 0x7fffu + ((v.u >> 16) & 1u);
  return (unsigned short)(r >> 16);
}

static __device__ __forceinline__ void gl_lds16(const void* g, void* l) {
  __builtin_amdgcn_global_load_lds((const __attribute__((address_space(1))) void*)g,
                                   (__attribute__((address_space(3))) void*)l, 16, 0, 0);
}

// XCD-pinning bijective swizzle: flat [0,4096) -> tile [0,1024), dg [0,4)
static __device__ __forceinline__ void xcd_tile_dg(int flat, int& tile, int& dg) {
  int w8 = flat >> 3, xl = flat & 7;
  tile = ((w8 >> 2) << 3) | xl;
  dg = w8 & 3;
}

// 2-sibling variant: flat [0,2048) -> tile [0,1024), dg [0,2)
static __device__ __forceinline__ void xcd_tile_dg2(int flat, int& tile, int& dg) {
  int w8 = flat >> 3, xl = flat & 7;
  tile = ((w8 >> 1) << 3) | xl;
  dg = w8 & 1;
}

// ---------------- K0: twiddle tables ----------------
__global__ __launch_bounds__(256) void k0_tables(const int* __restrict__ panel, float* __restrict__ tab) {
  __shared__ int kt[MP], kh[MP];
  int tid = threadIdx.x;
  if (tid < MP) { int s = panel[tid]; kt[tid] = s >> 5; kh[tid] = s & 31; }
  __syncthreads();
  const double PI2 = 6.283185307179586476925286766559;
  for (int i = tid; i < 1024; i += 256) {  // FT [p][t]
    int p = i >> 4, t = i & 15;
    double a = -PI2 * (double)((t * kt[p]) & 15) / 16.0;
    tab[OFF_FTRE + i] = (float)cos(a);
    tab[OFF_FTIM + i] = (float)sin(a);
  }
  for (int i = tid; i < 2048; i += 256) {  // FH [p][hs]
    int p = i >> 5, hs = i & 31;
    double a = -PI2 * (double)((hs * kh[p]) & 31) / 32.0;
    tab[OFF_FHRE + i] = (float)cos(a);
    tab[OFF_FHIM + i] = (float)sin(a);
  }
  for (int i = tid; i < 1024; i += 256) {  // CW [f][ws]
    int f = i >> 6, wsx = i & 63;
    double a = PI2 * (double)((f * wsx) & 63) / 64.0;
    tab[OFF_CW + i] = (f == 0) ? (1.0f / 64.0f) : (float)(2.0 * cos(a) / 64.0);
  }
  for (int i = tid; i < 2048; i += 256) {  // W64I [ws][f2]
    int wsx = i >> 5, f2 = i & 31; int f = f2 >> 1;
    double a = -PI2 * (double)((wsx * f) & 63) / 64.0;
    tab[OFF_W64I + i] = (f2 & 1) ? (float)sin(a) : (float)cos(a);
  }
  if (tid < 256) {                         // W16 [t][kt] float2
    int t = tid >> 4, k = tid & 15;
    double a = -PI2 * (double)((t * k) & 15) / 16.0;
    tab[OFF_W16 + 2 * tid]     = (float)cos(a);
    tab[OFF_W16 + 2 * tid + 1] = (float)sin(a);
  }
  for (int i = tid; i < 2048; i += 256) {  // FHT [hs][p] float2
    int hs = i >> 6, p = i & 63;
    double a = -PI2 * (double)((hs * kh[p]) & 31) / 32.0;
    tab[OFF_FHT + 2 * i]     = (float)cos(a);
    tab[OFF_FHT + 2 * i + 1] = (float)sin(a);
  }
}

// ---------------- conv_w: Wq/Wo fp32 [k][d] -> WT bf16 [d][k] ----------------
__global__ __launch_bounds__(256) void conv_w(const float* __restrict__ Wq, const float* __restrict__ Wo,
                                              unsigned short* __restrict__ wqt, unsigned short* __restrict__ wot) {
  __shared__ float tile[32][33];
  const float* src = blockIdx.z ? Wo : Wq;
  unsigned short* dst = blockIdx.z ? wot : wqt;
  int k0 = blockIdx.x * 32, d0 = blockIdx.y * 32;
  int tx = threadIdx.x & 31, r4 = threadIdx.x >> 5;
  #pragma unroll
  for (int it = 0; it < 4; it++) {
    int row = r4 + it * 8;
    tile[row][tx] = src[(size_t)(k0 + row) * 256 + d0 + tx];
  }
  __syncthreads();
  #pragma unroll
  for (int it = 0; it < 4; it++) {
    int row = r4 + it * 8;
    dst[(size_t)(d0 + row) * 256 + k0 + tx] = f2bf(tile[tx][row]);
  }
}

// ---------------- K1f4: Q=x@Wq+bq (bf16 MFMA, 128x128 tile, 8 waves) + reg-tiled ws-DFT -> Fw ----------------
// Flat grid 2048, XCD-pinned d-group pairs. LDS 43008 B.
__global__ __launch_bounds__(512) void k1f4(const float* __restrict__ x,
                                            const unsigned short* __restrict__ wqt,
                                            const float* __restrict__ bq,
                                            const float* __restrict__ tabp,
                                            float* __restrict__ Fwg) {
  __shared__ char smem[43008];
  char*  Al = smem;                      // [128 sp][128 B] bf16, XOR-swizzled (16384 B)
  char*  Bl = smem + 16384;              // [128 d][128 B] bf16, XOR-swizzled (16384 B)
  float* QL = (float*)smem;              // [64][136] fp32 overlay (34816 B)
  float* WL = (float*)(smem + 34816);    // [64 ws][32 f2] fp32 (8192 B, persistent)
  int tile, dg;
  xcd_tile_dg2(blockIdx.x, tile, dg);
  int d0 = dg << 7;
  int b = tile >> 8, st = tile & 255;
  int sp0 = st << 7;
  int tid = threadIdx.x;
  int lane = tid & 63, w = tid >> 6;       // 8 waves
  int l15 = lane & 15, kg = lane >> 4;
  int swz = (l15 & 7) << 4;
  for (int i = tid; i < 2048; i += 512) WL[i] = tabp[OFF_W64I + i];
  f32x4 acc[8];
  #pragma unroll
  for (int ni = 0; ni < 8; ni++) acc[ni] = (f32x4){0.f, 0.f, 0.f, 0.f};
  const float* xbase = x + ((size_t)b * 32768 + sp0) * 256;
  const char* Bbase = (const char*)(wqt + (size_t)d0 * 256);
  for (int k0 = 0; k0 < 256; k0 += 64) {
    // B-stage first: async gl_lds in flight during the A convert below
    #pragma unroll
    for (int it = 0; it < 2; it++) {
      int o = it * 8192 + tid * 16;
      int row = o >> 7, cb = o & 127;
      gl_lds16(Bbase + (size_t)row * 512 + k0 * 2 + (cb ^ ((row & 7) << 4)), Bl + o);
    }
    // A-stage: x fp32 -> bf16 -> swizzled LDS (in-register convert)
    #pragma unroll
    for (int it = 0; it < 2; it++) {
      int idx = it * 512 + tid;
      int row = idx >> 3, g8 = idx & 7;
      const float* src = xbase + (size_t)row * 256 + k0 + g8 * 8;
      float4 a4 = *reinterpret_cast<const float4*>(src);
      float4 b4 = *reinterpret_cast<const float4*>(src + 4);
      short8 v;
      v[0] = (short)f2bf(a4.x); v[1] = (short)f2bf(a4.y); v[2] = (short)f2bf(a4.z); v[3] = (short)f2bf(a4.w);
      v[4] = (short)f2bf(b4.x); v[5] = (short)f2bf(b4.y); v[6] = (short)f2bf(b4.z); v[7] = (short)f2bf(b4.w);
      int byteoff = (row * 128 + g8 * 16) ^ ((row & 7) << 4);
      *reinterpret_cast<short8*>(Al + byteoff) = v;
    }
    __syncthreads();
    #pragma unroll
    for (int ks = 0; ks < 2; ks++) {
      int koff = (ks * 64 + kg * 16) ^ swz;
      short8 af = *reinterpret_cast<const short8*>(Al + (w * 16 + l15) * 128 + koff);
      #pragma unroll
      for (int ni = 0; ni < 8; ni++) {
        short8 bfr = *reinterpret_cast<const short8*>(Bl + (ni * 16 + l15) * 128 + koff);
        acc[ni] = __builtin_amdgcn_mfma_f32_16x16x32_bf16(af, bfr, acc[ni], 0, 0, 0);
      }
    }
    __syncthreads();
  }
  // phase 2, split by s-half: QL[64][136] holds one s-row (64 ws) x 128 d of Q at a time.
  #pragma unroll
  for (int sh = 0; sh < 2; sh++) {
    if ((w >> 2) == sh) {                 // waves sh*4..sh*4+3 own this s-half's rows
      #pragma unroll
      for (int ni = 0; ni < 8; ni++) {
        float bqv = bq[d0 + ni * 16 + l15];
        f32x4 vv = acc[ni];
        int m = (w & 3) * 16 + kg * 4;    // row within this s-half (0..63)
        #pragma unroll
        for (int j = 0; j < 4; j++)
          QL[(m + j) * 136 + ni * 16 + l15] = vv[j] + bqv;
      }
    }
    __syncthreads();
    // DFT for this s: thread = (d-pair 0..63, f2-quad 0..7); 2d x 4f2 outputs each
    {
      int dp = tid >> 3, f2q = tid & 7;
      f32x4 a0 = (f32x4){0.f, 0.f, 0.f, 0.f};
      f32x4 a1 = (f32x4){0.f, 0.f, 0.f, 0.f};
      const float* qbase = QL + dp * 2;
      const float* wbase = WL + f2q * 4;
      #pragma unroll 8
      for (int wsx = 0; wsx < 64; wsx++) {
        float2 q = *reinterpret_cast<const float2*>(qbase + wsx * 136);
        f32x4 wv = *reinterpret_cast<const f32x4*>(wbase + wsx * 32);
        a0 += wv * q.x;
        a1 += wv * q.y;
      }
      int sgl = st * 2 + sh;
      size_t g0 = ((size_t)(b * 512 + sgl) * 256 + d0 + dp * 2) * 32 + f2q * 4;
      *reinterpret_cast<f32x4*>(&Fwg[g0]) = a0;
      *reinterpret_cast<f32x4*>(&Fwg[g0 + 32]) = a1;
    }
    if (sh == 0) __syncthreads();  // QL reused by second half
  }
}

// ---------------- K3f: per (b,d): t-DFT (in-place LDS) + selected hs-reduction -> X[bd][p][f] ----------------
__global__ __launch_bounds__(512) void k3f(const float* __restrict__ Fwg, const float* __restrict__ tabp,
                                           const int* __restrict__ panel, float* __restrict__ X) {
  __shared__ float2 Floc[8192];   // 64 KB
  __shared__ float2 fhT[32][64];  // 16 KB
  __shared__ float2 W16L[16][16]; // 2 KB
  __shared__ int ktl[64];
  int bd = blockIdx.x; int b = bd >> 8; int d = bd & 255;
  int tid = threadIdx.x;
  if (tid < 256) W16L[tid >> 4][tid & 15] = reinterpret_cast<const float2*>(tabp + OFF_W16)[tid];
  for (int i = tid; i < 2048; i += 512) fhT[i >> 6][i & 63] = reinterpret_cast<const float2*>(tabp + OFF_FHT)[i];
  if (tid < 64) ktl[tid] = panel[tid] >> 5;
  {
    const char* gb = (const char*)Fwg;
    #pragma unroll
    for (int r = 0; r < 8; r++) {
      int o = r * 8192 + tid * 16;
      int s = o >> 7; int c16 = (o >> 4) & 7;
      size_t gaddr = ((size_t)(b * 512 + s) * 256 + d) * 128 + (size_t)c16 * 16;
      gl_lds16(gb + gaddr, (char*)Floc + o);
    }
  }
  __syncthreads();
  int hs = tid >> 4, f = tid & 15;
  float2 v[16];
  #pragma unroll
  for (int t = 0; t < 16; t++) v[t] = Floc[(t * 32 + hs) * 16 + f];
  float2 a[16];
  #pragma unroll
  for (int k = 0; k < 16; k++) a[k] = make_float2(0.f, 0.f);
  #pragma unroll
  for (int t = 0; t < 16; t++) {
    float2 vv = v[t];
    #pragma unroll
    for (int k = 0; k < 16; k++) {
      float2 w = W16L[t][k];
      a[k].x += w.x * vv.x - w.y * vv.y;
      a[k].y += w.x * vv.y + w.y * vv.x;
    }
  }
  #pragma unroll
  for (int k = 0; k < 16; k++) Floc[(k * 32 + hs) * 16 + f] = a[k];
  __syncthreads();
  int p2 = tid >> 4;
  float2 res[2];
  #pragma unroll
  for (int half = 0; half < 2; half++) {
    int p = p2 + half * 32;
    int kt = ktl[p];
    float ar = 0.f, ai = 0.f;
    #pragma unroll 8
    for (int h = 0; h < 32; h++) {
      float2 e = fhT[h][p];
      float2 u = Floc[(kt * 32 + h) * 16 + f];
      ar += u.x * e.x - u.y * e.y;
      ai += u.x * e.y + u.y * e.x;
    }
    res[half] = make_float2(ar, ai);
  }
  float2* Xo = reinterpret_cast<float2*>(X) + (size_t)bd * 1024;
  Xo[p2 * 16 + f] = res[0];
  Xo[(p2 + 32) * 16 + f] = res[1];
}

// ---------------- K3b: mode mix out_sel = sum_i x_sel * w ----------------
__global__ __launch_bounds__(512) void k3b_mix(const float* __restrict__ X, const float* __restrict__ wreal,
                                               const float* __restrict__ wimag, float* __restrict__ V) {
  __shared__ float2 xs[4][32][16];
  int h = blockIdx.x >> 6;
  int p = blockIdx.x & 63;
  int tid = threadIdx.x;
  const float2* Xv = reinterpret_cast<const float2*>(X);
  for (int i = tid; i < 2048; i += 512) {
    int b = i >> 9, ii = (i >> 4) & 31, f = i & 15;
    xs[b][ii][f] = Xv[((size_t)(b * 256 + h * 32 + ii) * MP + p) * ML + f];
  }
  __syncthreads();
  int o = tid >> 4, f = tid & 15;
  float accr[4] = {0, 0, 0, 0}, acci[4] = {0, 0, 0, 0};
  for (int i = 0; i < 32; i++) {
    size_t wofs = ((((size_t)h * 32 + i) * 32 + o) * MP + p) * ML + f;
    float wr = wreal[wofs], wi = wimag[wofs];
    #pragma unroll
    for (int b = 0; b < 4; b++) {
      float2 xv = xs[b][i][f];
      accr[b] += xv.x * wr - xv.y * wi;
      acci[b] += xv.x * wi + xv.y * wr;
    }
  }
  #pragma unroll
  for (int b = 0; b < 4; b++)
    reinterpret_cast<float2*>(V)[((size_t)(b * 256 + h * 32 + o) * MP + p) * ML + f] =
        make_float2(accr[b], acci[b]);
}

// ---------------- K4a: inverse spatial DFT -> G[b][c][s][f] (fp32, global) ----------------
__global__ __launch_bounds__(256) void k4a_inv(const float* __restrict__ V, const float* __restrict__ tabp,
                                               float* __restrict__ gbuf) {
  __shared__ float2 vl[64][16];
  __shared__ float2 ft[64][16];
  __shared__ float2 fh[64][32];
  int bd = blockIdx.x;
  int tid = threadIdx.x;
  const float2* Vv = reinterpret_cast<const float2*>(V) + (size_t)bd * MP * ML;
  for (int i = tid; i < 1024; i += 256) {
    vl[i >> 4][i & 15] = Vv[i];
    ft[i >> 4][i & 15] = make_float2(tabp[OFF_FTRE + i], tabp[OFF_FTIM + i]);
  }
  for (int i = tid; i < 2048; i += 256) fh[i >> 5][i & 31] = make_float2(tabp[OFF_FHRE + i], tabp[OFF_FHIM + i]);
  __syncthreads();
  float g0[16], g1[16];
  #pragma unroll
  for (int f = 0; f < 16; f++) { g0[f] = 0.f; g1[f] = 0.f; }
  int s0 = tid * 2;
  int t0 = s0 >> 5, hs0 = s0 & 31;
  int t1 = (s0 + 1) >> 5, hs1 = (s0 + 1) & 31;
  for (int p = 0; p < 64; p++) {
    float2 et0 = ft[p][t0], eh0 = fh[p][hs0];
    float2 et1 = ft[p][t1], eh1 = fh[p][hs1];
    float er0 = et0.x * eh0.x - et0.y * eh0.y;
    float ei0 = et0.x * eh0.y + et0.y * eh0.x;
    float er1 = et1.x * eh1.x - et1.y * eh1.y;
    float ei1 = et1.x * eh1.y + et1.y * eh1.x;
    #pragma unroll
    for (int f = 0; f < 16; f++) {
      float2 v = vl[p][f];
      g0[f] += v.x * er0 + v.y * ei0;
      g1[f] += v.x * er1 + v.y * ei1;
    }
  }
  float4* gb = reinterpret_cast<float4*>(gbuf + (size_t)bd * 8192 + (size_t)s0 * 16);
  #pragma unroll
  for (int q = 0; q < 4; q++)
    gb[q] = make_float4(g0[q * 4] * (1.f / 512.f), g0[q * 4 + 1] * (1.f / 512.f),
                        g0[q * 4 + 2] * (1.f / 512.f), g0[q * 4 + 3] * (1.f / 512.f));
  #pragma unroll
  for (int q = 0; q < 4; q++)
    gb[4 + q] = make_float4(g1[q * 4] * (1.f / 512.f), g1[q * 4 + 1] * (1.f / 512.f),
                            g1[q * 4 + 2] * (1.f / 512.f), g1[q * 4 + 3] * (1.f / 512.f));
}

// ---------------- K4b: o[b][sp][c] bf16 = sum_f G[b][c][s][f] * cw[f][ws] ----------------
__global__ __launch_bounds__(256) void k4b_cos(const float* __restrict__ gbuf, const float* __restrict__ tabp,
                                               unsigned short* __restrict__ ob) {
  __shared__ float Gs[256][17];
  __shared__ float cwL[16][64];
  int s = blockIdx.x, b = blockIdx.y;
  int tid = threadIdx.x;
  for (int i = tid; i < 4096; i += 256) {
    int c = i >> 4, f = i & 15;
    Gs[c][f] = gbuf[(size_t)(b * 256 + c) * 8192 + s * 16 + f];
  }
  for (int i = tid; i < 1024; i += 256) cwL[i >> 6][i & 63] = tabp[OFF_CW + i];
  __syncthreads();
  int c0 = (tid & 63) * 4, wsg = tid >> 6;
  float gv[4][16];
  #pragma unroll
  for (int j = 0; j < 4; j++)
    #pragma unroll
    for (int f = 0; f < 16; f++) gv[j][f] = Gs[c0 + j][f];
  for (int wsi = 0; wsi < 16; wsi++) {
    int wsx = wsg * 16 + wsi;
    float a0 = 0.f, a1 = 0.f, a2 = 0.f, a3 = 0.f;
    #pragma unroll
    for (int f = 0; f < 16; f++) {
      float cwv = cwL[f][wsx];
      a0 += gv[0][f] * cwv; a1 += gv[1][f] * cwv; a2 += gv[2][f] * cwv; a3 += gv[3][f] * cwv;
    }
    ushort4 u;
    u.x = f2bf(a0); u.y = f2bf(a1); u.z = f2bf(a2); u.w = f2bf(a3);
    *reinterpret_cast<ushort4*>(&ob[((size_t)b * SPAT + (size_t)s * 64 + wsx) * 256 + c0]) = u;
  }
}

// ---------------- K5: out = o @ Wo + bo via bf16 MFMA, out fp32 [b][sp][d] ----------------
__global__ __launch_bounds__(256) void k5_mfma(const unsigned short* __restrict__ ob,
                                               const unsigned short* __restrict__ wot,
                                               const float* __restrict__ bo, float* __restrict__ out) {
  __shared__ char smem[34816];
  unsigned short* Al = (unsigned short*)smem;           // 16384 B
  unsigned short* Bl = (unsigned short*)(smem + 16384); // 8192 B
  float* OL = (float*)smem;                             // [128][68] fp32 epilogue overlay
  int tile, dg;
  xcd_tile_dg(blockIdx.x, tile, dg);
  int b = tile >> 8, sp0 = (tile & 255) << 7, d0 = dg << 6;
  int tid = threadIdx.x;
  int lane = tid & 63, w = tid >> 6;
  int l15 = lane & 15, kg = lane >> 4;
  int swz = (l15 & 7) << 4;
  f32x4 acc[2][4];
  #pragma unroll
  for (int mi = 0; mi < 2; mi++)
    #pragma unroll
    for (int ni = 0; ni < 4; ni++) acc[mi][ni] = (f32x4){0.f, 0.f, 0.f, 0.f};
  const char* Abase = (const char*)(ob + ((size_t)b * 32768 + sp0) * 256);
  const char* Bbase = (const char*)(wot + (size_t)d0 * 256);
  for (int k0 = 0; k0 < 256; k0 += 64) {
    #pragma unroll
    for (int it = 0; it < 2; it++) {
      int o = tid * 16 + it * 4096 + 16384;  // Bl region
      int ol = o - 16384;
      int row = ol >> 7, cb = ol & 127;
      int scb = cb ^ ((row & 7) << 4);
      gl_lds16(Bbase + (size_t)row * 512 + k0 * 2 + scb, smem + o);
    }
    #pragma unroll
    for (int it = 0; it < 4; it++) {
      int o = tid * 16 + it * 4096;
      int row = o >> 7, cb = o & 127;
      int scb = cb ^ ((row & 7) << 4);
      gl_lds16(Abase + (size_t)row * 512 + k0 * 2 + scb, (char*)Al + o);
    }
    __syncthreads();
    #pragma unroll
    for (int ks = 0; ks < 2; ks++) {
      int koff = (ks * 64 + kg * 16) ^ swz;
      short8 af[2], bfr[4];
      #pragma unroll
      for (int mi = 0; mi < 2; mi++)
        af[mi] = *(const short8*)((const char*)Al + (w * 32 + mi * 16 + l15) * 128 + koff);
      #pragma unroll
      for (int ni = 0; ni < 4; ni++)
        bfr[ni] = *(const short8*)((const char*)Bl + (ni * 16 + l15) * 128 + koff);
      #pragma unroll
      for (int mi = 0; mi < 2; mi++)
        #pragma unroll
        for (int ni = 0; ni < 4; ni++)
          acc[mi][ni] = __builtin_amdgcn_mfma_f32_16x16x32_bf16(af[mi], bfr[ni], acc[mi][ni], 0, 0, 0);
    }
    __syncthreads();
  }
  // epilogue via LDS for coalesced 256B stores
  #pragma unroll
  for (int ni = 0; ni < 4; ni++) {
    float bov = bo[d0 + ni * 16 + l15];
    #pragma unroll
    for (int mi = 0; mi < 2; mi++) {
      f32x4 v = acc[mi][ni];
      int m = w * 32 + mi * 16 + kg * 4;
      #pragma unroll
      for (int j = 0; j < 4; j++)
        OL[(m + j) * 68 + ni * 16 + l15] = v[j] + bov;
    }
  }
  __syncthreads();
  int f4 = tid & 15, r0 = tid >> 4;
  #pragma unroll
  for (int r = 0; r < 8; r++) {
    int m = r * 16 + r0;
    float4 val = *reinterpret_cast<const float4*>(&OL[m * 68 + f4 * 4]);
    *reinterpret_cast<float4*>(&out[((size_t)b * SPAT + sp0 + m) * 256 + d0 + f4 * 4]) = val;
  }
}

extern "C" void kernel_launch(void* const* d_in, const int* in_sizes, int n_in,
                              void* d_out, int out_size, void* d_ws, size_t ws_size,
                              hipStream_t stream) {
  const float* x  = (const float*)d_in[0];
  const float* Wq = (const float*)d_in[1];
  const float* bq = (const float*)d_in[2];
  // d_in[3..6] = Wk,bk,Wv,bv -- dead in the reference, skipped
  const float* Wo = (const float*)d_in[7];
  const float* bo = (const float*)d_in[8];
  const float* wr = (const float*)d_in[9];
  const float* wi = (const float*)d_in[10];
  const int* panel = (const int*)d_in[11];
  float* wsf = (float*)d_ws;
  float* out = (float*)d_out;

  float*          gbuf = wsf + OFF_GB;
  unsigned short* obb  = (unsigned short*)(wsf + OFF_FW);  // FW region dead after k3f
  unsigned short* wqt  = (unsigned short*)(wsf + OFF_WT);
  unsigned short* wot  = wqt + 65536;

  k0_tables<<<dim3(1), dim3(256), 0, stream>>>(panel, wsf);
  conv_w<<<dim3(8, 8, 2), dim3(256), 0, stream>>>(Wq, Wo, wqt, wot);
  k1f4<<<dim3(2048), dim3(512), 0, stream>>>(x, wqt, bq, wsf, wsf + OFF_FW);
  k3f<<<dim3(1024), dim3(512), 0, stream>>>(wsf + OFF_FW, wsf, panel, wsf + OFF_X);
  k3b_mix<<<dim3(512), dim3(512), 0, stream>>>(wsf + OFF_X, wr, wi, wsf + OFF_V);
  k4a_inv<<<dim3(1024), dim3(256), 0, stream>>>(wsf + OFF_V, wsf, gbuf);
  k4b_cos<<<dim3(512, 4), dim3(256), 0, stream>>>(gbuf, wsf, obb);
  k5_mfma<<<dim3(4096), dim3(256), 0, stream>>>(obb, wot, bo, out);
}

// Round 17
// 320.588 us; speedup vs baseline: 1.3239x; 1.0294x over previous
//
#include <hip/hip_runtime.h>
#include <hip/hip_bf16.h>
#include <cmath>

// Problem constants
#define BB 4
#define TT 16
#define HH 32
#define WW 64
#define DD 256
#define NHEAD 8
#define EE 32
#define MP 64      // M_PANEL
#define ML 16      // M_LAST
#define SPAT 32768 // TT*HH*WW
#define S2D 512    // TT*HH

// d_ws layout (float offsets)
constexpr size_t OFF_FTRE = 0;        // [p][t] 64x16
constexpr size_t OFF_FTIM = 1024;
constexpr size_t OFF_FHRE = 2048;     // [p][hs] 64x32
constexpr size_t OFF_FHIM = 4096;
constexpr size_t OFF_CW   = 6144;     // [f][ws] 16x64
constexpr size_t OFF_W64I = 7168;     // [ws][f2] 64x32 interleaved re,im
constexpr size_t OFF_W16  = 9216;     // [t][kt] float2 16x16
constexpr size_t OFF_FHT  = 9728;     // [hs][p] float2 32x64
constexpr size_t OFF_GB   = 16384;                 // gbuf fp32 [b][c][s][f] 8.4M floats
constexpr size_t OFF_FW   = OFF_GB + 8388608;      // Fw fp32 [b][s][d][f2] 16.8M floats; after k3f reused: ob bf16
constexpr size_t OFF_X    = OFF_FW + 16777216;     // [bd][p][f] cplx 2.1M floats
constexpr size_t OFF_V    = OFF_X + 2097152;       // [bd][p][f] cplx 2.1M floats
constexpr size_t OFF_WT   = OFF_V + 2097152;       // WqT bf16 65536 + WoT bf16 65536

typedef short short8 __attribute__((ext_vector_type(8)));
typedef float f32x4 __attribute__((ext_vector_type(4)));

static __device__ __forceinline__ unsigned short f2bf(float x) {
  union { float f; unsigned u; } v; v.f = x;
  unsigned r = v.u + 0x7fffu + ((v.u >> 16) & 1u);
  return (unsigned short)(r >> 16);
}

static __device__ __forceinline__ void gl_lds16(const void* g, void* l) {
  __builtin_amdgcn_global_load_lds((const __attribute__((address_space(1))) void*)g,
                                   (__attribute__((address_space(3))) void*)l, 16, 0, 0);
}

// XCD-pinning bijective swizzle: flat [0,4096) -> tile [0,1024), dg [0,4)
static __device__ __forceinline__ void xcd_tile_dg(int flat, int& tile, int& dg) {
  int w8 = flat >> 3, xl = flat & 7;
  tile = ((w8 >> 2) << 3) | xl;
  dg = w8 & 3;
}

// 2-sibling variant: flat [0,2048) -> tile [0,1024), dg [0,2)
static __device__ __forceinline__ void xcd_tile_dg2(int flat, int& tile, int& dg) {
  int w8 = flat >> 3, xl = flat & 7;
  tile = ((w8 >> 1) << 3) | xl;
  dg = w8 & 1;
}

// ---------------- K0: twiddle tables ----------------
__global__ __launch_bounds__(256) void k0_tables(const int* __restrict__ panel, float* __restrict__ tab) {
  __shared__ int kt[MP], kh[MP];
  int tid = threadIdx.x;
  if (tid < MP) { int s = panel[tid]; kt[tid] = s >> 5; kh[tid] = s & 31; }
  __syncthreads();
  const double PI2 = 6.283185307179586476925286766559;
  for (int i = tid; i < 1024; i += 256) {  // FT [p][t]
    int p = i >> 4, t = i & 15;
    double a = -PI2 * (double)((t * kt[p]) & 15) / 16.0;
    tab[OFF_FTRE + i] = (float)cos(a);
    tab[OFF_FTIM + i] = (float)sin(a);
  }
  for (int i = tid; i < 2048; i += 256) {  // FH [p][hs]
    int p = i >> 5, hs = i & 31;
    double a = -PI2 * (double)((hs * kh[p]) & 31) / 32.0;
    tab[OFF_FHRE + i] = (float)cos(a);
    tab[OFF_FHIM + i] = (float)sin(a);
  }
  for (int i = tid; i < 1024; i += 256) {  // CW [f][ws]
    int f = i >> 6, wsx = i & 63;
    double a = PI2 * (double)((f * wsx) & 63) / 64.0;
    tab[OFF_CW + i] = (f == 0) ? (1.0f / 64.0f) : (float)(2.0 * cos(a) / 64.0);
  }
  for (int i = tid; i < 2048; i += 256) {  // W64I [ws][f2]
    int wsx = i >> 5, f2 = i & 31; int f = f2 >> 1;
    double a = -PI2 * (double)((wsx * f) & 63) / 64.0;
    tab[OFF_W64I + i] = (f2 & 1) ? (float)sin(a) : (float)cos(a);
  }
  if (tid < 256) {                         // W16 [t][kt] float2
    int t = tid >> 4, k = tid & 15;
    double a = -PI2 * (double)((t * k) & 15) / 16.0;
    tab[OFF_W16 + 2 * tid]     = (float)cos(a);
    tab[OFF_W16 + 2 * tid + 1] = (float)sin(a);
  }
  for (int i = tid; i < 2048; i += 256) {  // FHT [hs][p] float2
    int hs = i >> 6, p = i & 63;
    double a = -PI2 * (double)((hs * kh[p]) & 31) / 32.0;
    tab[OFF_FHT + 2 * i]     = (float)cos(a);
    tab[OFF_FHT + 2 * i + 1] = (float)sin(a);
  }
}

// ---------------- conv_w: Wq/Wo fp32 [k][d] -> WT bf16 [d][k] ----------------
__global__ __launch_bounds__(256) void conv_w(const float* __restrict__ Wq, const float* __restrict__ Wo,
                                              unsigned short* __restrict__ wqt, unsigned short* __restrict__ wot) {
  __shared__ float tile[32][33];
  const float* src = blockIdx.z ? Wo : Wq;
  unsigned short* dst = blockIdx.z ? wot : wqt;
  int k0 = blockIdx.x * 32, d0 = blockIdx.y * 32;
  int tx = threadIdx.x & 31, r4 = threadIdx.x >> 5;
  #pragma unroll
  for (int it = 0; it < 4; it++) {
    int row = r4 + it * 8;
    tile[row][tx] = src[(size_t)(k0 + row) * 256 + d0 + tx];
  }
  __syncthreads();
  #pragma unroll
  for (int it = 0; it < 4; it++) {
    int row = r4 + it * 8;
    dst[(size_t)(d0 + row) * 256 + k0 + tx] = f2bf(tile[tx][row]);
  }
}

// ---------------- K1f4: Q=x@Wq+bq (bf16 MFMA, 128x128 tile, 8 waves) + single-pass reg-tiled ws-DFT ----------------
// Flat grid 2048, XCD-pinned d-group pairs. LDS 75776 B -> 2 blocks/CU (16 waves).
__global__ __launch_bounds__(512) void k1f4(const float* __restrict__ x,
                                            const unsigned short* __restrict__ wqt,
                                            const float* __restrict__ bq,
                                            const float* __restrict__ tabp,
                                            float* __restrict__ Fwg) {
  __shared__ char smem[75776];
  char*  Al = smem;                      // [128 sp][128 B] bf16, XOR-swizzled (16384 B)
  char*  Bl = smem + 16384;              // [128 d][128 B] bf16, XOR-swizzled (16384 B)
  float* QL = (float*)smem;              // [128][132] fp32 overlay (67584 B)
  float* WL = (float*)(smem + 67584);    // [64 ws][32 f2] fp32 (8192 B, persistent)
  int tile, dg;
  xcd_tile_dg2(blockIdx.x, tile, dg);
  int d0 = dg << 7;
  int b = tile >> 8, st = tile & 255;
  int sp0 = st << 7;
  int tid = threadIdx.x;
  int lane = tid & 63, w = tid >> 6;       // 8 waves
  int l15 = lane & 15, kg = lane >> 4;
  int swz = (l15 & 7) << 4;
  for (int i = tid; i < 2048; i += 512) WL[i] = tabp[OFF_W64I + i];
  f32x4 acc[8];
  #pragma unroll
  for (int ni = 0; ni < 8; ni++) acc[ni] = (f32x4){0.f, 0.f, 0.f, 0.f};
  const float* xbase = x + ((size_t)b * 32768 + sp0) * 256;
  const char* Bbase = (const char*)(wqt + (size_t)d0 * 256);
  for (int k0 = 0; k0 < 256; k0 += 64) {
    // B-stage first: async gl_lds in flight during the A convert below
    #pragma unroll
    for (int it = 0; it < 2; it++) {
      int o = it * 8192 + tid * 16;
      int row = o >> 7, cb = o & 127;
      gl_lds16(Bbase + (size_t)row * 512 + k0 * 2 + (cb ^ ((row & 7) << 4)), Bl + o);
    }
    // A-stage: x fp32 -> bf16 -> swizzled LDS (in-register convert)
    #pragma unroll
    for (int it = 0; it < 2; it++) {
      int idx = it * 512 + tid;
      int row = idx >> 3, g8 = idx & 7;
      const float* src = xbase + (size_t)row * 256 + k0 + g8 * 8;
      float4 a4 = *reinterpret_cast<const float4*>(src);
      float4 b4 = *reinterpret_cast<const float4*>(src + 4);
      short8 v;
      v[0] = (short)f2bf(a4.x); v[1] = (short)f2bf(a4.y); v[2] = (short)f2bf(a4.z); v[3] = (short)f2bf(a4.w);
      v[4] = (short)f2bf(b4.x); v[5] = (short)f2bf(b4.y); v[6] = (short)f2bf(b4.z); v[7] = (short)f2bf(b4.w);
      int byteoff = (row * 128 + g8 * 16) ^ ((row & 7) << 4);
      *reinterpret_cast<short8*>(Al + byteoff) = v;
    }
    __syncthreads();
    #pragma unroll
    for (int ks = 0; ks < 2; ks++) {
      int koff = (ks * 64 + kg * 16) ^ swz;
      short8 af = *reinterpret_cast<const short8*>(Al + (w * 16 + l15) * 128 + koff);
      #pragma unroll
      for (int ni = 0; ni < 8; ni++) {
        short8 bfr = *reinterpret_cast<const short8*>(Bl + (ni * 16 + l15) * 128 + koff);
        acc[ni] = __builtin_amdgcn_mfma_f32_16x16x32_bf16(af, bfr, acc[ni], 0, 0, 0);
      }
    }
    __syncthreads();
  }
  // phase 2a: all waves write Q (+bias) -> QL [128][132]
  #pragma unroll
  for (int ni = 0; ni < 8; ni++) {
    float bqv = bq[d0 + ni * 16 + l15];
    f32x4 vv = acc[ni];
    int m = w * 16 + kg * 4;
    #pragma unroll
    for (int j = 0; j < 4; j++)
      QL[(m + j) * 132 + ni * 16 + l15] = vv[j] + bqv;
  }
  __syncthreads();
  // phase 2b: single-pass DFT; thread = (sg, d-quad 0..31, f2-quad 0..7) -> 4d x 4f2
  {
    int sg = tid >> 8, rem = tid & 255;
    int dp = rem >> 3, f2q = rem & 7;
    f32x4 a2[4];
    a2[0] = (f32x4){0.f, 0.f, 0.f, 0.f};
    a2[1] = (f32x4){0.f, 0.f, 0.f, 0.f};
    a2[2] = (f32x4){0.f, 0.f, 0.f, 0.f};
    a2[3] = (f32x4){0.f, 0.f, 0.f, 0.f};
    const float* qbase = QL + (sg * 64) * 132 + dp * 4;
    const float* wbase = WL + f2q * 4;
    #pragma unroll 8
    for (int wsx = 0; wsx < 64; wsx++) {
      f32x4 q  = *reinterpret_cast<const f32x4*>(qbase + wsx * 132);
      f32x4 wv = *reinterpret_cast<const f32x4*>(wbase + wsx * 32);
      a2[0] += wv * q[0];
      a2[1] += wv * q[1];
      a2[2] += wv * q[2];
      a2[3] += wv * q[3];
    }
    int sgl = st * 2 + sg;
    size_t g0 = ((size_t)(b * 512 + sgl) * 256 + d0 + dp * 4) * 32 + f2q * 4;
    #pragma unroll
    for (int di = 0; di < 4; di++)
      *reinterpret_cast<f32x4*>(&Fwg[g0 + (size_t)di * 32]) = a2[di];
  }
}

// ---------------- K3f: per (b,d): t-DFT (in-place LDS) + selected hs-reduction -> X[bd][p][f] ----------------
__global__ __launch_bounds__(512) void k3f(const float* __restrict__ Fwg, const float* __restrict__ tabp,
                                           const int* __restrict__ panel, float* __restrict__ X) {
  __shared__ float2 Floc[8192];   // 64 KB
  __shared__ float2 fhT[32][64];  // 16 KB
  __shared__ float2 W16L[16][16]; // 2 KB
  __shared__ int ktl[64];
  int bd = blockIdx.x; int b = bd >> 8; int d = bd & 255;
  int tid = threadIdx.x;
  if (tid < 256) W16L[tid >> 4][tid & 15] = reinterpret_cast<const float2*>(tabp + OFF_W16)[tid];
  for (int i = tid; i < 2048; i += 512) fhT[i >> 6][i & 63] = reinterpret_cast<const float2*>(tabp + OFF_FHT)[i];
  if (tid < 64) ktl[tid] = panel[tid] >> 5;
  {
    const char* gb = (const char*)Fwg;
    #pragma unroll
    for (int r = 0; r < 8; r++) {
      int o = r * 8192 + tid * 16;
      int s = o >> 7; int c16 = (o >> 4) & 7;
      size_t gaddr = ((size_t)(b * 512 + s) * 256 + d) * 128 + (size_t)c16 * 16;
      gl_lds16(gb + gaddr, (char*)Floc + o);
    }
  }
  __syncthreads();
  int hs = tid >> 4, f = tid & 15;
  float2 v[16];
  #pragma unroll
  for (int t = 0; t < 16; t++) v[t] = Floc[(t * 32 + hs) * 16 + f];
  float2 a[16];
  #pragma unroll
  for (int k = 0; k < 16; k++) a[k] = make_float2(0.f, 0.f);
  #pragma unroll
  for (int t = 0; t < 16; t++) {
    float2 vv = v[t];
    #pragma unroll
    for (int k = 0; k < 16; k++) {
      float2 w = W16L[t][k];
      a[k].x += w.x * vv.x - w.y * vv.y;
      a[k].y += w.x * vv.y + w.y * vv.x;
    }
  }
  #pragma unroll
  for (int k = 0; k < 16; k++) Floc[(k * 32 + hs) * 16 + f] = a[k];
  __syncthreads();
  int p2 = tid >> 4;
  float2 res[2];
  #pragma unroll
  for (int half = 0; half < 2; half++) {
    int p = p2 + half * 32;
    int kt = ktl[p];
    float ar = 0.f, ai = 0.f;
    #pragma unroll 8
    for (int h = 0; h < 32; h++) {
      float2 e = fhT[h][p];
      float2 u = Floc[(kt * 32 + h) * 16 + f];
      ar += u.x * e.x - u.y * e.y;
      ai += u.x * e.y + u.y * e.x;
    }
    res[half] = make_float2(ar, ai);
  }
  float2* Xo = reinterpret_cast<float2*>(X) + (size_t)bd * 1024;
  Xo[p2 * 16 + f] = res[0];
  Xo[(p2 + 32) * 16 + f] = res[1];
}

// ---------------- K3b: mode mix out_sel = sum_i x_sel * w ----------------
__global__ __launch_bounds__(512) void k3b_mix(const float* __restrict__ X, const float* __restrict__ wreal,
                                               const float* __restrict__ wimag, float* __restrict__ V) {
  __shared__ float2 xs[4][32][16];
  int h = blockIdx.x >> 6;
  int p = blockIdx.x & 63;
  int tid = threadIdx.x;
  const float2* Xv = reinterpret_cast<const float2*>(X);
  for (int i = tid; i < 2048; i += 512) {
    int b = i >> 9, ii = (i >> 4) & 31, f = i & 15;
    xs[b][ii][f] = Xv[((size_t)(b * 256 + h * 32 + ii) * MP + p) * ML + f];
  }
  __syncthreads();
  int o = tid >> 4, f = tid & 15;
  float accr[4] = {0, 0, 0, 0}, acci[4] = {0, 0, 0, 0};
  for (int i = 0; i < 32; i++) {
    size_t wofs = ((((size_t)h * 32 + i) * 32 + o) * MP + p) * ML + f;
    float wr = wreal[wofs], wi = wimag[wofs];
    #pragma unroll
    for (int b = 0; b < 4; b++) {
      float2 xv = xs[b][i][f];
      accr[b] += xv.x * wr - xv.y * wi;
      acci[b] += xv.x * wi + xv.y * wr;
    }
  }
  #pragma unroll
  for (int b = 0; b < 4; b++)
    reinterpret_cast<float2*>(V)[((size_t)(b * 256 + h * 32 + o) * MP + p) * ML + f] =
        make_float2(accr[b], acci[b]);
}

// ---------------- K4a: inverse spatial DFT -> G[b][c][s][f] (fp32, global) ----------------
__global__ __launch_bounds__(256) void k4a_inv(const float* __restrict__ V, const float* __restrict__ tabp,
                                               float* __restrict__ gbuf) {
  __shared__ float2 vl[64][16];
  __shared__ float2 ft[64][16];
  __shared__ float2 fh[64][32];
  int bd = blockIdx.x;
  int tid = threadIdx.x;
  const float2* Vv = reinterpret_cast<const float2*>(V) + (size_t)bd * MP * ML;
  for (int i = tid; i < 1024; i += 256) {
    vl[i >> 4][i & 15] = Vv[i];
    ft[i >> 4][i & 15] = make_float2(tabp[OFF_FTRE + i], tabp[OFF_FTIM + i]);
  }
  for (int i = tid; i < 2048; i += 256) fh[i >> 5][i & 31] = make_float2(tabp[OFF_FHRE + i], tabp[OFF_FHIM + i]);
  __syncthreads();
  float g0[16], g1[16];
  #pragma unroll
  for (int f = 0; f < 16; f++) { g0[f] = 0.f; g1[f] = 0.f; }
  int s0 = tid * 2;
  int t0 = s0 >> 5, hs0 = s0 & 31;
  int t1 = (s0 + 1) >> 5, hs1 = (s0 + 1) & 31;
  for (int p = 0; p < 64; p++) {
    float2 et0 = ft[p][t0], eh0 = fh[p][hs0];
    float2 et1 = ft[p][t1], eh1 = fh[p][hs1];
    float er0 = et0.x * eh0.x - et0.y * eh0.y;
    float ei0 = et0.x * eh0.y + et0.y * eh0.x;
    float er1 = et1.x * eh1.x - et1.y * eh1.y;
    float ei1 = et1.x * eh1.y + et1.y * eh1.x;
    #pragma unroll
    for (int f = 0; f < 16; f++) {
      float2 v = vl[p][f];
      g0[f] += v.x * er0 + v.y * ei0;
      g1[f] += v.x * er1 + v.y * ei1;
    }
  }
  float4* gb = reinterpret_cast<float4*>(gbuf + (size_t)bd * 8192 + (size_t)s0 * 16);
  #pragma unroll
  for (int q = 0; q < 4; q++)
    gb[q] = make_float4(g0[q * 4] * (1.f / 512.f), g0[q * 4 + 1] * (1.f / 512.f),
                        g0[q * 4 + 2] * (1.f / 512.f), g0[q * 4 + 3] * (1.f / 512.f));
  #pragma unroll
  for (int q = 0; q < 4; q++)
    gb[4 + q] = make_float4(g1[q * 4] * (1.f / 512.f), g1[q * 4 + 1] * (1.f / 512.f),
                            g1[q * 4 + 2] * (1.f / 512.f), g1[q * 4 + 3] * (1.f / 512.f));
}

// ---------------- K4b: o[b][sp][c] bf16 = sum_f G[b][c][s][f] * cw[f][ws] ----------------
__global__ __launch_bounds__(256) void k4b_cos(const float* __restrict__ gbuf, const float* __restrict__ tabp,
                                               unsigned short* __restrict__ ob) {
  __shared__ float Gs[256][17];
  __shared__ float cwL[16][64];
  int s = blockIdx.x, b = blockIdx.y;
  int tid = threadIdx.x;
  for (int i = tid; i < 4096; i += 256) {
    int c = i >> 4, f = i & 15;
    Gs[c][f] = gbuf[(size_t)(b * 256 + c) * 8192 + s * 16 + f];
  }
  for (int i = tid; i < 1024; i += 256) cwL[i >> 6][i & 63] = tabp[OFF_CW + i];
  __syncthreads();
  int c0 = (tid & 63) * 4, wsg = tid >> 6;
  float gv[4][16];
  #pragma unroll
  for (int j = 0; j < 4; j++)
    #pragma unroll
    for (int f = 0; f < 16; f++) gv[j][f] = Gs[c0 + j][f];
  for (int wsi = 0; wsi < 16; wsi++) {
    int wsx = wsg * 16 + wsi;
    float a0 = 0.f, a1 = 0.f, a2 = 0.f, a3 = 0.f;
    #pragma unroll
    for (int f = 0; f < 16; f++) {
      float cwv = cwL[f][wsx];
      a0 += gv[0][f] * cwv; a1 += gv[1][f] * cwv; a2 += gv[2][f] * cwv; a3 += gv[3][f] * cwv;
    }
    ushort4 u;
    u.x = f2bf(a0); u.y = f2bf(a1); u.z = f2bf(a2); u.w = f2bf(a3);
    *reinterpret_cast<ushort4*>(&ob[((size_t)b * SPAT + (size_t)s * 64 + wsx) * 256 + c0]) = u;
  }
}

// ---------------- K5: out = o @ Wo + bo via bf16 MFMA, out fp32 [b][sp][d] ----------------
__global__ __launch_bounds__(256) void k5_mfma(const unsigned short* __restrict__ ob,
                                               const unsigned short* __restrict__ wot,
                                               const float* __restrict__ bo, float* __restrict__ out) {
  __shared__ char smem[34816];
  unsigned short* Al = (unsigned short*)smem;           // 16384 B
  unsigned short* Bl = (unsigned short*)(smem + 16384); // 8192 B
  float* OL = (float*)smem;                             // [128][68] fp32 epilogue overlay
  int tile, dg;
  xcd_tile_dg(blockIdx.x, tile, dg);
  int b = tile >> 8, sp0 = (tile & 255) << 7, d0 = dg << 6;
  int tid = threadIdx.x;
  int lane = tid & 63, w = tid >> 6;
  int l15 = lane & 15, kg = lane >> 4;
  int swz = (l15 & 7) << 4;
  f32x4 acc[2][4];
  #pragma unroll
  for (int mi = 0; mi < 2; mi++)
    #pragma unroll
    for (int ni = 0; ni < 4; ni++) acc[mi][ni] = (f32x4){0.f, 0.f, 0.f, 0.f};
  const char* Abase = (const char*)(ob + ((size_t)b * 32768 + sp0) * 256);
  const char* Bbase = (const char*)(wot + (size_t)d0 * 256);
  for (int k0 = 0; k0 < 256; k0 += 64) {
    #pragma unroll
    for (int it = 0; it < 2; it++) {
      int o = tid * 16 + it * 4096 + 16384;  // Bl region
      int ol = o - 16384;
      int row = ol >> 7, cb = ol & 127;
      int scb = cb ^ ((row & 7) << 4);
      gl_lds16(Bbase + (size_t)row * 512 + k0 * 2 + scb, smem + o);
    }
    #pragma unroll
    for (int it = 0; it < 4; it++) {
      int o = tid * 16 + it * 4096;
      int row = o >> 7, cb = o & 127;
      int scb = cb ^ ((row & 7) << 4);
      gl_lds16(Abase + (size_t)row * 512 + k0 * 2 + scb, (char*)Al + o);
    }
    __syncthreads();
    #pragma unroll
    for (int ks = 0; ks < 2; ks++) {
      int koff = (ks * 64 + kg * 16) ^ swz;
      short8 af[2], bfr[4];
      #pragma unroll
      for (int mi = 0; mi < 2; mi++)
        af[mi] = *(const short8*)((const char*)Al + (w * 32 + mi * 16 + l15) * 128 + koff);
      #pragma unroll
      for (int ni = 0; ni < 4; ni++)
        bfr[ni] = *(const short8*)((const char*)Bl + (ni * 16 + l15) * 128 + koff);
      #pragma unroll
      for (int mi = 0; mi < 2; mi++)
        #pragma unroll
        for (int ni = 0; ni < 4; ni++)
          acc[mi][ni] = __builtin_amdgcn_mfma_f32_16x16x32_bf16(af[mi], bfr[ni], acc[mi][ni], 0, 0, 0);
    }
    __syncthreads();
  }
  // epilogue via LDS for coalesced 256B stores
  #pragma unroll
  for (int ni = 0; ni < 4; ni++) {
    float bov = bo[d0 + ni * 16 + l15];
    #pragma unroll
    for (int mi = 0; mi < 2; mi++) {
      f32x4 v = acc[mi][ni];
      int m = w * 32 + mi * 16 + kg * 4;
      #pragma unroll
      for (int j = 0; j < 4; j++)
        OL[(m + j) * 68 + ni * 16 + l15] = v[j] + bov;
    }
  }
  __syncthreads();
  int f4 = tid & 15, r0 = tid >> 4;
  #pragma unroll
  for (int r = 0; r < 8; r++) {
    int m = r * 16 + r0;
    float4 val = *reinterpret_cast<const float4*>(&OL[m * 68 + f4 * 4]);
    *reinterpret_cast<float4*>(&out[((size_t)b * SPAT + sp0 + m) * 256 + d0 + f4 * 4]) = val;
  }
}

extern "C" void kernel_launch(void* const* d_in, const int* in_sizes, int n_in,
                              void* d_out, int out_size, void* d_ws, size_t ws_size,
                              hipStream_t stream) {
  const float* x  = (const float*)d_in[0];
  const float* Wq = (const float*)d_in[1];
  const float* bq = (const float*)d_in[2];
  // d_in[3..6] = Wk,bk,Wv,bv -- dead in the reference, skipped
  const float* Wo = (const float*)d_in[7];
  const float* bo = (const float*)d_in[8];
  const float* wr = (const float*)d_in[9];
  const float* wi = (const float*)d_in[10];
  const int* panel = (const int*)d_in[11];
  float* wsf = (float*)d_ws;
  float* out = (float*)d_out;

  float*          gbuf = wsf + OFF_GB;
  unsigned short* obb  = (unsigned short*)(wsf + OFF_FW);  // FW region dead after k3f
  unsigned short* wqt  = (unsigned short*)(wsf + OFF_WT);
  unsigned short* wot  = wqt + 65536;

  k0_tables<<<dim3(1), dim3(256), 0, stream>>>(panel, wsf);
  conv_w<<<dim3(8, 8, 2), dim3(256), 0, stream>>>(Wq, Wo, wqt, wot);
  k1f4<<<dim3(2048), dim3(512), 0, stream>>>(x, wqt, bq, wsf, wsf + OFF_FW);
  k3f<<<dim3(1024), dim3(512), 0, stream>>>(wsf + OFF_FW, wsf, panel, wsf + OFF_X);
  k3b_mix<<<dim3(512), dim3(512), 0, stream>>>(wsf + OFF_X, wr, wi, wsf + OFF_V);
  k4a_inv<<<dim3(1024), dim3(256), 0, stream>>>(wsf + OFF_V, wsf, gbuf);
  k4b_cos<<<dim3(512, 4), dim3(256), 0, stream>>>(gbuf, wsf, obb);
  k5_mfma<<<dim3(4096), dim3(256), 0, stream>>>(obb, wot, bo, out);
}

// Round 18
// 302.235 us; speedup vs baseline: 1.4043x; 1.0607x over previous
//
#include <hip/hip_runtime.h>
#include <hip/hip_bf16.h>
#include <cmath>

// Problem constants
#define BB 4
#define TT 16
#define HH 32
#define WW 64
#define DD 256
#define NHEAD 8
#define EE 32
#define MP 64      // M_PANEL
#define ML 16      // M_LAST
#define SPAT 32768 // TT*HH*WW
#define S2D 512    // TT*HH

// d_ws layout (float offsets)
constexpr size_t OFF_FTRE = 0;        // [p][t] 64x16
constexpr size_t OFF_FTIM = 1024;
constexpr size_t OFF_FHRE = 2048;     // [p][hs] 64x32
constexpr size_t OFF_FHIM = 4096;
constexpr size_t OFF_CW   = 6144;     // [f][ws] 16x64
constexpr size_t OFF_W64I = 7168;     // [ws][f2] 64x32 interleaved re,im
constexpr size_t OFF_W16  = 9216;     // [t][kt] float2 16x16
constexpr size_t OFF_FHT  = 9728;     // [hs][p] float2 32x64
constexpr size_t OFF_GB   = 16384;                 // gbuf fp32 [b][c][s][f] 8.4M floats
constexpr size_t OFF_FW   = OFF_GB + 8388608;      // Fw fp32 [b][s][d][f2] 16.8M floats
constexpr size_t OFF_X    = OFF_FW + 16777216;     // [bd][p][f] cplx 2.1M floats
constexpr size_t OFF_V    = OFF_X + 2097152;       // [bd][p][f] cplx 2.1M floats
constexpr size_t OFF_WT   = OFF_V + 2097152;       // WqT bf16 65536 + WoT bf16 65536

typedef short short8 __attribute__((ext_vector_type(8)));
typedef float f32x4 __attribute__((ext_vector_type(4)));

static __device__ __forceinline__ unsigned short f2bf(float x) {
  union { float f; unsigned u; } v; v.f = x;
  unsigned r = v.u + 0x7fffu + ((v.u >> 16) & 1u);
  return (unsigned short)(r >> 16);
}

static __device__ __forceinline__ void gl_lds16(const void* g, void* l) {
  __builtin_amdgcn_global_load_lds((const __attribute__((address_space(1))) void*)g,
                                   (__attribute__((address_space(3))) void*)l, 16, 0, 0);
}

// XCD-pinning bijective swizzle: flat [0,4096) -> tile [0,1024), dg [0,4)
static __device__ __forceinline__ void xcd_tile_dg(int flat, int& tile, int& dg) {
  int w8 = flat >> 3, xl = flat & 7;
  tile = ((w8 >> 2) << 3) | xl;
  dg = w8 & 3;
}

// 2-sibling variant: flat [0,2048) -> tile [0,1024), dg [0,2)
static __device__ __forceinline__ void xcd_tile_dg2(int flat, int& tile, int& dg) {
  int w8 = flat >> 3, xl = flat & 7;
  tile = ((w8 >> 1) << 3) | xl;
  dg = w8 & 1;
}

// ---------------- K0: twiddle tables ----------------
__global__ __launch_bounds__(256) void k0_tables(const int* __restrict__ panel, float* __restrict__ tab) {
  __shared__ int kt[MP], kh[MP];
  int tid = threadIdx.x;
  if (tid < MP) { int s = panel[tid]; kt[tid] = s >> 5; kh[tid] = s & 31; }
  __syncthreads();
  const double PI2 = 6.283185307179586476925286766559;
  for (int i = tid; i < 1024; i += 256) {  // FT [p][t]
    int p = i >> 4, t = i & 15;
    double a = -PI2 * (double)((t * kt[p]) & 15) / 16.0;
    tab[OFF_FTRE + i] = (float)cos(a);
    tab[OFF_FTIM + i] = (float)sin(a);
  }
  for (int i = tid; i < 2048; i += 256) {  // FH [p][hs]
    int p = i >> 5, hs = i & 31;
    double a = -PI2 * (double)((hs * kh[p]) & 31) / 32.0;
    tab[OFF_FHRE + i] = (float)cos(a);
    tab[OFF_FHIM + i] = (float)sin(a);
  }
  for (int i = tid; i < 1024; i += 256) {  // CW [f][ws]
    int f = i >> 6, wsx = i & 63;
    double a = PI2 * (double)((f * wsx) & 63) / 64.0;
    tab[OFF_CW + i] = (f == 0) ? (1.0f / 64.0f) : (float)(2.0 * cos(a) / 64.0);
  }
  for (int i = tid; i < 2048; i += 256) {  // W64I [ws][f2]
    int wsx = i >> 5, f2 = i & 31; int f = f2 >> 1;
    double a = -PI2 * (double)((wsx * f) & 63) / 64.0;
    tab[OFF_W64I + i] = (f2 & 1) ? (float)sin(a) : (float)cos(a);
  }
  if (tid < 256) {                         // W16 [t][kt] float2
    int t = tid >> 4, k = tid & 15;
    double a = -PI2 * (double)((t * k) & 15) / 16.0;
    tab[OFF_W16 + 2 * tid]     = (float)cos(a);
    tab[OFF_W16 + 2 * tid + 1] = (float)sin(a);
  }
  for (int i = tid; i < 2048; i += 256) {  // FHT [hs][p] float2
    int hs = i >> 6, p = i & 63;
    double a = -PI2 * (double)((hs * kh[p]) & 31) / 32.0;
    tab[OFF_FHT + 2 * i]     = (float)cos(a);
    tab[OFF_FHT + 2 * i + 1] = (float)sin(a);
  }
}

// ---------------- conv_w: Wq/Wo fp32 [k][d] -> WT bf16 [d][k] ----------------
__global__ __launch_bounds__(256) void conv_w(const float* __restrict__ Wq, const float* __restrict__ Wo,
                                              unsigned short* __restrict__ wqt, unsigned short* __restrict__ wot) {
  __shared__ float tile[32][33];
  const float* src = blockIdx.z ? Wo : Wq;
  unsigned short* dst = blockIdx.z ? wot : wqt;
  int k0 = blockIdx.x * 32, d0 = blockIdx.y * 32;
  int tx = threadIdx.x & 31, r4 = threadIdx.x >> 5;
  #pragma unroll
  for (int it = 0; it < 4; it++) {
    int row = r4 + it * 8;
    tile[row][tx] = src[(size_t)(k0 + row) * 256 + d0 + tx];
  }
  __syncthreads();
  #pragma unroll
  for (int it = 0; it < 4; it++) {
    int row = r4 + it * 8;
    dst[(size_t)(d0 + row) * 256 + k0 + tx] = f2bf(tile[tx][row]);
  }
}

// ---------------- K1f4: Q=x@Wq+bq (bf16 MFMA, 128x128 tile, 8 waves) + single-pass reg-tiled ws-DFT ----------------
// Flat grid 2048, XCD-pinned d-group pairs. LDS 75776 B -> 2 blocks/CU (16 waves). (round-17 proven)
__global__ __launch_bounds__(512) void k1f4(const float* __restrict__ x,
                                            const unsigned short* __restrict__ wqt,
                                            const float* __restrict__ bq,
                                            const float* __restrict__ tabp,
                                            float* __restrict__ Fwg) {
  __shared__ char smem[75776];
  char*  Al = smem;                      // [128 sp][128 B] bf16, XOR-swizzled (16384 B)
  char*  Bl = smem + 16384;              // [128 d][128 B] bf16, XOR-swizzled (16384 B)
  float* QL = (float*)smem;              // [128][132] fp32 overlay (67584 B)
  float* WL = (float*)(smem + 67584);    // [64 ws][32 f2] fp32 (8192 B, persistent)
  int tile, dg;
  xcd_tile_dg2(blockIdx.x, tile, dg);
  int d0 = dg << 7;
  int b = tile >> 8, st = tile & 255;
  int sp0 = st << 7;
  int tid = threadIdx.x;
  int lane = tid & 63, w = tid >> 6;       // 8 waves
  int l15 = lane & 15, kg = lane >> 4;
  int swz = (l15 & 7) << 4;
  for (int i = tid; i < 2048; i += 512) WL[i] = tabp[OFF_W64I + i];
  f32x4 acc[8];
  #pragma unroll
  for (int ni = 0; ni < 8; ni++) acc[ni] = (f32x4){0.f, 0.f, 0.f, 0.f};
  const float* xbase = x + ((size_t)b * 32768 + sp0) * 256;
  const char* Bbase = (const char*)(wqt + (size_t)d0 * 256);
  for (int k0 = 0; k0 < 256; k0 += 64) {
    #pragma unroll
    for (int it = 0; it < 2; it++) {
      int o = it * 8192 + tid * 16;
      int row = o >> 7, cb = o & 127;
      gl_lds16(Bbase + (size_t)row * 512 + k0 * 2 + (cb ^ ((row & 7) << 4)), Bl + o);
    }
    #pragma unroll
    for (int it = 0; it < 2; it++) {
      int idx = it * 512 + tid;
      int row = idx >> 3, g8 = idx & 7;
      const float* src = xbase + (size_t)row * 256 + k0 + g8 * 8;
      float4 a4 = *reinterpret_cast<const float4*>(src);
      float4 b4 = *reinterpret_cast<const float4*>(src + 4);
      short8 v;
      v[0] = (short)f2bf(a4.x); v[1] = (short)f2bf(a4.y); v[2] = (short)f2bf(a4.z); v[3] = (short)f2bf(a4.w);
      v[4] = (short)f2bf(b4.x); v[5] = (short)f2bf(b4.y); v[6] = (short)f2bf(b4.z); v[7] = (short)f2bf(b4.w);
      int byteoff = (row * 128 + g8 * 16) ^ ((row & 7) << 4);
      *reinterpret_cast<short8*>(Al + byteoff) = v;
    }
    __syncthreads();
    #pragma unroll
    for (int ks = 0; ks < 2; ks++) {
      int koff = (ks * 64 + kg * 16) ^ swz;
      short8 af = *reinterpret_cast<const short8*>(Al + (w * 16 + l15) * 128 + koff);
      #pragma unroll
      for (int ni = 0; ni < 8; ni++) {
        short8 bfr = *reinterpret_cast<const short8*>(Bl + (ni * 16 + l15) * 128 + koff);
        acc[ni] = __builtin_amdgcn_mfma_f32_16x16x32_bf16(af, bfr, acc[ni], 0, 0, 0);
      }
    }
    __syncthreads();
  }
  #pragma unroll
  for (int ni = 0; ni < 8; ni++) {
    float bqv = bq[d0 + ni * 16 + l15];
    f32x4 vv = acc[ni];
    int m = w * 16 + kg * 4;
    #pragma unroll
    for (int j = 0; j < 4; j++)
      QL[(m + j) * 132 + ni * 16 + l15] = vv[j] + bqv;
  }
  __syncthreads();
  {
    int sg = tid >> 8, rem = tid & 255;
    int dp = rem >> 3, f2q = rem & 7;
    f32x4 a2[4];
    a2[0] = (f32x4){0.f, 0.f, 0.f, 0.f};
    a2[1] = (f32x4){0.f, 0.f, 0.f, 0.f};
    a2[2] = (f32x4){0.f, 0.f, 0.f, 0.f};
    a2[3] = (f32x4){0.f, 0.f, 0.f, 0.f};
    const float* qbase = QL + (sg * 64) * 132 + dp * 4;
    const float* wbase = WL + f2q * 4;
    #pragma unroll 8
    for (int wsx = 0; wsx < 64; wsx++) {
      f32x4 q  = *reinterpret_cast<const f32x4*>(qbase + wsx * 132);
      f32x4 wv = *reinterpret_cast<const f32x4*>(wbase + wsx * 32);
      a2[0] += wv * q[0];
      a2[1] += wv * q[1];
      a2[2] += wv * q[2];
      a2[3] += wv * q[3];
    }
    int sgl = st * 2 + sg;
    size_t g0 = ((size_t)(b * 512 + sgl) * 256 + d0 + dp * 4) * 32 + f2q * 4;
    #pragma unroll
    for (int di = 0; di < 4; di++)
      *reinterpret_cast<f32x4*>(&Fwg[g0 + (size_t)di * 32]) = a2[di];
  }
}

// ---------------- K3f: per (b,d): t-DFT (in-place LDS) + selected hs-reduction -> X[bd][p][f] ----------------
__global__ __launch_bounds__(512) void k3f(const float* __restrict__ Fwg, const float* __restrict__ tabp,
                                           const int* __restrict__ panel, float* __restrict__ X) {
  __shared__ float2 Floc[8192];   // 64 KB
  __shared__ float2 fhT[32][64];  // 16 KB
  __shared__ float2 W16L[16][16]; // 2 KB
  __shared__ int ktl[64];
  int bd = blockIdx.x; int b = bd >> 8; int d = bd & 255;
  int tid = threadIdx.x;
  if (tid < 256) W16L[tid >> 4][tid & 15] = reinterpret_cast<const float2*>(tabp + OFF_W16)[tid];
  for (int i = tid; i < 2048; i += 512) fhT[i >> 6][i & 63] = reinterpret_cast<const float2*>(tabp + OFF_FHT)[i];
  if (tid < 64) ktl[tid] = panel[tid] >> 5;
  {
    const char* gb = (const char*)Fwg;
    #pragma unroll
    for (int r = 0; r < 8; r++) {
      int o = r * 8192 + tid * 16;
      int s = o >> 7; int c16 = (o >> 4) & 7;
      size_t gaddr = ((size_t)(b * 512 + s) * 256 + d) * 128 + (size_t)c16 * 16;
      gl_lds16(gb + gaddr, (char*)Floc + o);
    }
  }
  __syncthreads();
  int hs = tid >> 4, f = tid & 15;
  float2 v[16];
  #pragma unroll
  for (int t = 0; t < 16; t++) v[t] = Floc[(t * 32 + hs) * 16 + f];
  float2 a[16];
  #pragma unroll
  for (int k = 0; k < 16; k++) a[k] = make_float2(0.f, 0.f);
  #pragma unroll
  for (int t = 0; t < 16; t++) {
    float2 vv = v[t];
    #pragma unroll
    for (int k = 0; k < 16; k++) {
      float2 w = W16L[t][k];
      a[k].x += w.x * vv.x - w.y * vv.y;
      a[k].y += w.x * vv.y + w.y * vv.x;
    }
  }
  #pragma unroll
  for (int k = 0; k < 16; k++) Floc[(k * 32 + hs) * 16 + f] = a[k];
  __syncthreads();
  int p2 = tid >> 4;
  float2 res[2];
  #pragma unroll
  for (int half = 0; half < 2; half++) {
    int p = p2 + half * 32;
    int kt = ktl[p];
    float ar = 0.f, ai = 0.f;
    #pragma unroll 8
    for (int h = 0; h < 32; h++) {
      float2 e = fhT[h][p];
      float2 u = Floc[(kt * 32 + h) * 16 + f];
      ar += u.x * e.x - u.y * e.y;
      ai += u.x * e.y + u.y * e.x;
    }
    res[half] = make_float2(ar, ai);
  }
  float2* Xo = reinterpret_cast<float2*>(X) + (size_t)bd * 1024;
  Xo[p2 * 16 + f] = res[0];
  Xo[(p2 + 32) * 16 + f] = res[1];
}

// ---------------- K3b: mode mix out_sel = sum_i x_sel * w ----------------
__global__ __launch_bounds__(512) void k3b_mix(const float* __restrict__ X, const float* __restrict__ wreal,
                                               const float* __restrict__ wimag, float* __restrict__ V) {
  __shared__ float2 xs[4][32][16];
  int h = blockIdx.x >> 6;
  int p = blockIdx.x & 63;
  int tid = threadIdx.x;
  const float2* Xv = reinterpret_cast<const float2*>(X);
  for (int i = tid; i < 2048; i += 512) {
    int b = i >> 9, ii = (i >> 4) & 31, f = i & 15;
    xs[b][ii][f] = Xv[((size_t)(b * 256 + h * 32 + ii) * MP + p) * ML + f];
  }
  __syncthreads();
  int o = tid >> 4, f = tid & 15;
  float accr[4] = {0, 0, 0, 0}, acci[4] = {0, 0, 0, 0};
  for (int i = 0; i < 32; i++) {
    size_t wofs = ((((size_t)h * 32 + i) * 32 + o) * MP + p) * ML + f;
    float wr = wreal[wofs], wi = wimag[wofs];
    #pragma unroll
    for (int b = 0; b < 4; b++) {
      float2 xv = xs[b][i][f];
      accr[b] += xv.x * wr - xv.y * wi;
      acci[b] += xv.x * wi + xv.y * wr;
    }
  }
  #pragma unroll
  for (int b = 0; b < 4; b++)
    reinterpret_cast<float2*>(V)[((size_t)(b * 256 + h * 32 + o) * MP + p) * ML + f] =
        make_float2(accr[b], acci[b]);
}

// ---------------- K4a: inverse spatial DFT -> G[b][c][s][f] (fp32, global) ----------------
__global__ __launch_bounds__(256) void k4a_inv(const float* __restrict__ V, const float* __restrict__ tabp,
                                               float* __restrict__ gbuf) {
  __shared__ float2 vl[64][16];
  __shared__ float2 ft[64][16];
  __shared__ float2 fh[64][32];
  int bd = blockIdx.x;
  int tid = threadIdx.x;
  const float2* Vv = reinterpret_cast<const float2*>(V) + (size_t)bd * MP * ML;
  for (int i = tid; i < 1024; i += 256) {
    vl[i >> 4][i & 15] = Vv[i];
    ft[i >> 4][i & 15] = make_float2(tabp[OFF_FTRE + i], tabp[OFF_FTIM + i]);
  }
  for (int i = tid; i < 2048; i += 256) fh[i >> 5][i & 31] = make_float2(tabp[OFF_FHRE + i], tabp[OFF_FHIM + i]);
  __syncthreads();
  float g0[16], g1[16];
  #pragma unroll
  for (int f = 0; f < 16; f++) { g0[f] = 0.f; g1[f] = 0.f; }
  int s0 = tid * 2;
  int t0 = s0 >> 5, hs0 = s0 & 31;
  int t1 = (s0 + 1) >> 5, hs1 = (s0 + 1) & 31;
  for (int p = 0; p < 64; p++) {
    float2 et0 = ft[p][t0], eh0 = fh[p][hs0];
    float2 et1 = ft[p][t1], eh1 = fh[p][hs1];
    float er0 = et0.x * eh0.x - et0.y * eh0.y;
    float ei0 = et0.x * eh0.y + et0.y * eh0.x;
    float er1 = et1.x * eh1.x - et1.y * eh1.y;
    float ei1 = et1.x * eh1.y + et1.y * eh1.x;
    #pragma unroll
    for (int f = 0; f < 16; f++) {
      float2 v = vl[p][f];
      g0[f] += v.x * er0 + v.y * ei0;
      g1[f] += v.x * er1 + v.y * ei1;
    }
  }
  float4* gb = reinterpret_cast<float4*>(gbuf + (size_t)bd * 8192 + (size_t)s0 * 16);
  #pragma unroll
  for (int q = 0; q < 4; q++)
    gb[q] = make_float4(g0[q * 4] * (1.f / 512.f), g0[q * 4 + 1] * (1.f / 512.f),
                        g0[q * 4 + 2] * (1.f / 512.f), g0[q * 4 + 3] * (1.f / 512.f));
  #pragma unroll
  for (int q = 0; q < 4; q++)
    gb[4 + q] = make_float4(g1[q * 4] * (1.f / 512.f), g1[q * 4 + 1] * (1.f / 512.f),
                            g1[q * 4 + 2] * (1.f / 512.f), g1[q * 4 + 3] * (1.f / 512.f));
}

// ---------------- K5f2: fused cos-expansion + out = o @ Wo + bo (bf16 MFMA, M=64, d-looped) ----------------
// Block = one (b, s). Grid flat 2048, s-pairs XCD-pinned (G cache-line sharing).
// A built in LDS (chunked-swizzled [4 kc][64 ws][128B]); k4b's proven conflict-free patterns kept verbatim.
__global__ __launch_bounds__(256) void k5f2(const float* __restrict__ gbuf,
                                            const unsigned short* __restrict__ wot,
                                            const float* __restrict__ bo,
                                            const float* __restrict__ tabp,
                                            float* __restrict__ out) {
  __shared__ char smem[70656];
  float* Gs  = (float*)smem;              // [256][17] fp32 = 17408 B (dead after A-build)
  float* cwL = (float*)(smem + 17408);    // [16][64] = 4096 B
  char*  Asm = smem + 21504;              // [4 kc][64 ws][128 B] bf16 = 32768 B
  char*  Bl  = smem + 54272;              // [4 kc][32 d][128 B] bf16 = 16384 B
  float* OL  = (float*)smem;              // [64][36] fp32 overlay of Gs (9216 B)
  int tile, sh;
  xcd_tile_dg2(blockIdx.x, tile, sh);
  int b = tile >> 8, spair = tile & 255;
  int s = spair * 2 + sh;
  int tid = threadIdx.x;
  int lane = tid & 63, w = tid >> 6;
  int l15 = lane & 15, kg = lane >> 4;
  // phase 1: stage Gs[c][f] (k4b pattern) + cwL
  for (int i = tid; i < 4096; i += 256) {
    int c = i >> 4, f = i & 15;
    Gs[c * 17 + f] = gbuf[(size_t)(b * 256 + c) * 8192 + s * 16 + f];
  }
  for (int i = tid; i < 1024; i += 256) cwL[i] = tabp[OFF_CW + i];
  __syncthreads();
  // phase 2: cos-expansion -> A bf16 (k4b compute, LDS-redirected)
  {
    int c0 = (tid & 63) * 4, wsg = tid >> 6;
    float gv[4][16];
    #pragma unroll
    for (int j = 0; j < 4; j++)
      #pragma unroll
      for (int f = 0; f < 16; f++) gv[j][f] = Gs[(c0 + j) * 17 + f];
    for (int wsi = 0; wsi < 16; wsi++) {
      int wsx = wsg * 16 + wsi;
      float a0 = 0.f, a1 = 0.f, a2 = 0.f, a3 = 0.f;
      #pragma unroll
      for (int f = 0; f < 16; f++) {
        float cwv = cwL[f * 64 + wsx];
        a0 += gv[0][f] * cwv; a1 += gv[1][f] * cwv; a2 += gv[2][f] * cwv; a3 += gv[3][f] * cwv;
      }
      ushort4 u;
      u.x = f2bf(a0); u.y = f2bf(a1); u.z = f2bf(a2); u.w = f2bf(a3);
      int kbyte = c0 * 2;                   // 0..511
      int kc = kbyte >> 7, rem = kbyte & 127;
      int addr = kc * 8192 + wsx * 128 + (rem ^ ((wsx & 7) << 4));
      *reinterpret_cast<ushort4*>(Asm + addr) = u;
    }
  }
  // B stage for d-group 0 (chunked: chunk=(dgrp<<2)|kc; linear dest, inverse-swizzled source)
  const char* Bbase = (const char*)wot;
  {
    #pragma unroll
    for (int it = 0; it < 4; it++) {
      int chunk = it * 4 + w;
      int kc = chunk & 3, dgrp = chunk >> 2;
      int d = dgrp * 8 + (lane >> 3);
      int kbs = kc * 128 + (((lane & 7) << 4) ^ ((d & 7) << 4));
      gl_lds16(Bbase + (size_t)d * 512 + kbs, Bl + kc * 4096 + dgrp * 1024 + lane * 16);
    }
  }
  __syncthreads();
  float* outb = out + ((size_t)b * 32768 + (size_t)s * 64) * 256;
  for (int it8 = 0; it8 < 8; it8++) {
    int d0g = it8 * 32;
    f32x4 acc0 = (f32x4){0.f, 0.f, 0.f, 0.f};
    f32x4 acc1 = (f32x4){0.f, 0.f, 0.f, 0.f};
    #pragma unroll
    for (int step = 0; step < 8; step++) {
      int kc = step >> 1;
      int rembase = (step & 1) * 64 + kg * 16;
      int arow = w * 16 + l15;
      short8 af  = *reinterpret_cast<const short8*>(Asm + kc * 8192 + arow * 128 + (rembase ^ ((arow & 7) << 4)));
      short8 bf0 = *reinterpret_cast<const short8*>(Bl + kc * 4096 + l15 * 128 + (rembase ^ ((l15 & 7) << 4)));
      short8 bf1 = *reinterpret_cast<const short8*>(Bl + kc * 4096 + (16 + l15) * 128 + (rembase ^ (((16 + l15) & 7) << 4)));
      acc0 = __builtin_amdgcn_mfma_f32_16x16x32_bf16(af, bf0, acc0, 0, 0, 0);
      acc1 = __builtin_amdgcn_mfma_f32_16x16x32_bf16(af, bf1, acc1, 0, 0, 0);
    }
    {
      float bo0 = bo[d0g + l15];
      float bo1 = bo[d0g + 16 + l15];
      #pragma unroll
      for (int j = 0; j < 4; j++) {
        OL[(w * 16 + kg * 4 + j) * 36 + l15]      = acc0[j] + bo0;
        OL[(w * 16 + kg * 4 + j) * 36 + 16 + l15] = acc1[j] + bo1;
      }
    }
    __syncthreads();   // OL visible; Bl reads complete
    if (it8 < 7) {
      int dnext = (it8 + 1) * 32;
      #pragma unroll
      for (int it = 0; it < 4; it++) {
        int chunk = it * 4 + w;
        int kc = chunk & 3, dgrp = chunk >> 2;
        int d = dgrp * 8 + (lane >> 3);
        int kbs = kc * 128 + (((lane & 7) << 4) ^ ((d & 7) << 4));
        gl_lds16(Bbase + (size_t)(dnext + d) * 512 + kbs, Bl + kc * 4096 + dgrp * 1024 + lane * 16);
      }
    }
    #pragma unroll
    for (int rep = 0; rep < 2; rep++) {
      int row = (tid >> 3) + rep * 32;
      int f4 = tid & 7;
      float4 v = *reinterpret_cast<const float4*>(OL + row * 36 + f4 * 4);
      *reinterpret_cast<float4*>(outb + (size_t)row * 256 + d0g + f4 * 4) = v;
    }
    __syncthreads();   // OL stores done; next B staged (gl_lds drained)
  }
}

extern "C" void kernel_launch(void* const* d_in, const int* in_sizes, int n_in,
                              void* d_out, int out_size, void* d_ws, size_t ws_size,
                              hipStream_t stream) {
  const float* x  = (const float*)d_in[0];
  const float* Wq = (const float*)d_in[1];
  const float* bq = (const float*)d_in[2];
  // d_in[3..6] = Wk,bk,Wv,bv -- dead in the reference, skipped
  const float* Wo = (const float*)d_in[7];
  const float* bo = (const float*)d_in[8];
  const float* wr = (const float*)d_in[9];
  const float* wi = (const float*)d_in[10];
  const int* panel = (const int*)d_in[11];
  float* wsf = (float*)d_ws;
  float* out = (float*)d_out;

  float*          gbuf = wsf + OFF_GB;
  unsigned short* wqt  = (unsigned short*)(wsf + OFF_WT);
  unsigned short* wot  = wqt + 65536;

  k0_tables<<<dim3(1), dim3(256), 0, stream>>>(panel, wsf);
  conv_w<<<dim3(8, 8, 2), dim3(256), 0, stream>>>(Wq, Wo, wqt, wot);
  k1f4<<<dim3(2048), dim3(512), 0, stream>>>(x, wqt, bq, wsf, wsf + OFF_FW);
  k3f<<<dim3(1024), dim3(512), 0, stream>>>(wsf + OFF_FW, wsf, panel, wsf + OFF_X);
  k3b_mix<<<dim3(512), dim3(512), 0, stream>>>(wsf + OFF_X, wr, wi, wsf + OFF_V);
  k4a_inv<<<dim3(1024), dim3(256), 0, stream>>>(wsf + OFF_V, wsf, gbuf);
  k5f2<<<dim3(2048), dim3(256), 0, stream>>>(gbuf, wot, bo, wsf, out);
}